// Round 1
// baseline (1604.945 us; speedup 1.0000x reference)
//
#include <hip/hip_runtime.h>

#define N_NODES 100000
#define N_EDGES 600000
#define FEAT 128
#define NUM_RELS 8
#define NUM_BASES 4

// ws layout:
//   float W[8*128*128]        @ 0            (512 KB)  combined per-relation weights
//   int   meta[32]            @ +131072 f    [0..7]=cnt, [8..16]=bases(9), [17..24]=cursors
//   int   bucket[600512]      @ meta+32      edge ids grouped by relation, -1 = pad
// total ~2.9 MB

// ---------- k0: W[r] = sum_b w_comp[r,b] * weight[b]; zero the counters ----------
__global__ __launch_bounds__(256) void k_build_w(const float* __restrict__ weight,
                                                 const float* __restrict__ w_comp,
                                                 float* __restrict__ W,
                                                 int* __restrict__ meta) {
    if (blockIdx.x == 0 && threadIdx.x < NUM_RELS) meta[threadIdx.x] = 0;
    int idx = blockIdx.x * 256 + threadIdx.x;
    if (idx < NUM_RELS * FEAT * FEAT) {
        int r = idx >> 14;         // / 16384
        int e = idx & 16383;
        float acc = 0.f;
#pragma unroll
        for (int b = 0; b < NUM_BASES; ++b)
            acc += w_comp[r * NUM_BASES + b] * weight[b * FEAT * FEAT + e];
        W[idx] = acc;
    }
}

// ---------- k1: histogram rel counts; init bucket to -1 ----------
__global__ __launch_bounds__(256) void k_hist(const int* __restrict__ rel,
                                              int* __restrict__ meta,
                                              int* __restrict__ bucket) {
    __shared__ int hist[NUM_RELS];
    if (threadIdx.x < NUM_RELS) hist[threadIdx.x] = 0;
    __syncthreads();
    int i = blockIdx.x * 256 + threadIdx.x;
    if (i < 600512) bucket[i] = -1;
    if (i < N_EDGES) atomicAdd(&hist[rel[i]], 1);
    __syncthreads();
    if (threadIdx.x < NUM_RELS) atomicAdd(&meta[threadIdx.x], hist[threadIdx.x]);
}

// ---------- k2a: tiny scan -> 64-padded bases + cursors ----------
__global__ void k_scan(int* __restrict__ meta) {
    if (blockIdx.x == 0 && threadIdx.x == 0) {
        int acc = 0;
        for (int r = 0; r < NUM_RELS; ++r) {
            meta[8 + r]  = acc;   // base
            meta[17 + r] = acc;   // cursor
            acc += ((meta[r] + 63) >> 6) << 6;   // pad each region to x64
        }
        meta[16] = acc;           // bases[8] = padded total
    }
}

// ---------- k2b: scatter edge ids into relation buckets (wave-aggregated atomics) ----------
__global__ __launch_bounds__(256) void k_scatter(const int* __restrict__ rel,
                                                 int* __restrict__ meta,
                                                 int* __restrict__ bucket) {
    int i = blockIdx.x * 256 + threadIdx.x;
    bool valid = i < N_EDGES;
    int r = valid ? rel[i] : -1;
    int lane = threadIdx.x & 63;
    for (int rr = 0; rr < NUM_RELS; ++rr) {
        unsigned long long mask = __ballot(valid && (r == rr));
        if (mask == 0ull) continue;                      // wave-uniform
        int leader = __ffsll((unsigned long long)mask) - 1;
        int base = 0;
        if (lane == leader) base = atomicAdd(&meta[17 + rr], __popcll(mask));
        base = __shfl(base, leader);
        if (valid && (r == rr)) {
            int prefix = __popcll(mask & ((1ull << lane) - 1ull));
            bucket[base + prefix] = i;
        }
    }
}

// ---------- k3: out = h @ root_weight + bias  (64 nodes/block, 16/wave) ----------
__global__ __launch_bounds__(256) void k_root(const float* __restrict__ h,
                                              const float* __restrict__ rw,
                                              const float* __restrict__ bias,
                                              float* __restrict__ out) {
    __shared__ float lds[FEAT * FEAT];                   // 64 KB
    const float4* rw4 = (const float4*)rw;
    float4* lds4 = (float4*)lds;
#pragma unroll
    for (int t = 0; t < 16; ++t)
        lds4[threadIdx.x + t * 256] = rw4[threadIdx.x + t * 256];
    __syncthreads();

    int wave = threadIdx.x >> 6, lane = threadIdx.x & 63;
    int n0 = blockIdx.x * 64 + wave * 16;

    float hreg[16][2];
#pragma unroll
    for (int e = 0; e < 16; ++e) {
        int n = n0 + e; if (n >= N_NODES) n = N_NODES - 1;
        hreg[e][0] = h[n * FEAT + lane];
        hreg[e][1] = h[n * FEAT + lane + 64];
    }
    float b0 = bias[lane], b1 = bias[lane + 64];
    float acc0[16], acc1[16];
#pragma unroll
    for (int e = 0; e < 16; ++e) { acc0[e] = b0; acc1[e] = b1; }

#pragma unroll
    for (int half = 0; half < 2; ++half) {
        for (int ii = 0; ii < 64; ++ii) {
            int i = half * 64 + ii;
            float w0 = lds[i * FEAT + lane];
            float w1 = lds[i * FEAT + lane + 64];
#pragma unroll
            for (int e = 0; e < 16; ++e) {
                float hv = __int_as_float(
                    __builtin_amdgcn_readlane(__float_as_int(hreg[e][half]), ii));
                acc0[e] += hv * w0;
                acc1[e] += hv * w1;
            }
        }
    }
#pragma unroll
    for (int e = 0; e < 16; ++e) {
        int n = n0 + e;
        if (n < N_NODES) {
            out[n * FEAT + lane]      = acc0[e];
            out[n * FEAT + lane + 64] = acc1[e];
        }
    }
}

// ---------- k4: per-relation edge GEMV + atomic scatter (64 edges/block) ----------
__global__ __launch_bounds__(256) void k_edge(const float* __restrict__ h,
                                              const float* __restrict__ W,
                                              const int* __restrict__ srcI,
                                              const int* __restrict__ dstI,
                                              const int* __restrict__ meta,
                                              const int* __restrict__ bucket,
                                              float* __restrict__ out) {
    __shared__ float lds[FEAT * FEAT];                   // 64 KB
    const int* bases = meta + 8;
    int ntot = bases[8];
    int p0 = blockIdx.x * 64;
    if (p0 >= ntot) return;                              // block-uniform exit

    int rel = 0;
#pragma unroll
    for (int r = 1; r < NUM_RELS; ++r) if (p0 >= bases[r]) rel = r;

    const float4* w4 = (const float4*)(W + rel * FEAT * FEAT);
    float4* lds4 = (float4*)lds;
#pragma unroll
    for (int t = 0; t < 16; ++t)
        lds4[threadIdx.x + t * 256] = w4[threadIdx.x + t * 256];
    __syncthreads();

    int wave = threadIdx.x >> 6, lane = threadIdx.x & 63;
    int p = p0 + wave * 16;

    int dstn[16];
    float hreg[16][2];
#pragma unroll
    for (int e = 0; e < 16; ++e) {
        int eid = bucket[p + e];
        int sn = 0;
        if (eid >= 0) { sn = srcI[eid]; dstn[e] = dstI[eid]; }
        else          { dstn[e] = -1; }
        hreg[e][0] = h[sn * FEAT + lane];
        hreg[e][1] = h[sn * FEAT + lane + 64];
    }

    float acc0[16], acc1[16];
#pragma unroll
    for (int e = 0; e < 16; ++e) { acc0[e] = 0.f; acc1[e] = 0.f; }

#pragma unroll
    for (int half = 0; half < 2; ++half) {
        for (int ii = 0; ii < 64; ++ii) {
            int i = half * 64 + ii;
            float w0 = lds[i * FEAT + lane];
            float w1 = lds[i * FEAT + lane + 64];
#pragma unroll
            for (int e = 0; e < 16; ++e) {
                float hv = __int_as_float(
                    __builtin_amdgcn_readlane(__float_as_int(hreg[e][half]), ii));
                acc0[e] += hv * w0;
                acc1[e] += hv * w1;
            }
        }
    }
#pragma unroll
    for (int e = 0; e < 16; ++e) {
        if (dstn[e] >= 0) {
            atomicAdd(&out[dstn[e] * FEAT + lane],      acc0[e]);
            atomicAdd(&out[dstn[e] * FEAT + lane + 64], acc1[e]);
        }
    }
}

// ---------- k5: relu in place ----------
__global__ __launch_bounds__(256) void k_relu(float* __restrict__ out) {
    int i = blockIdx.x * 256 + threadIdx.x;
    if (i < N_NODES * FEAT / 4) {
        float4* o4 = (float4*)out;
        float4 v = o4[i];
        v.x = fmaxf(v.x, 0.f);
        v.y = fmaxf(v.y, 0.f);
        v.z = fmaxf(v.z, 0.f);
        v.w = fmaxf(v.w, 0.f);
        o4[i] = v;
    }
}

extern "C" void kernel_launch(void* const* d_in, const int* in_sizes, int n_in,
                              void* d_out, int out_size, void* d_ws, size_t ws_size,
                              hipStream_t stream) {
    const float* h    = (const float*)d_in[0];
    const float* wgt  = (const float*)d_in[1];
    const float* wcmp = (const float*)d_in[2];
    const float* rw   = (const float*)d_in[3];
    const float* bias = (const float*)d_in[4];
    const int*   src  = (const int*)d_in[5];
    const int*   dst  = (const int*)d_in[6];
    const int*   rel  = (const int*)d_in[7];
    float* out = (float*)d_out;

    float* W    = (float*)d_ws;
    int*   meta = (int*)(W + NUM_RELS * FEAT * FEAT);
    int*   bucket = meta + 32;

    hipLaunchKernelGGL(k_build_w, dim3(512),  dim3(256), 0, stream, wgt, wcmp, W, meta);
    hipLaunchKernelGGL(k_hist,    dim3(2347), dim3(256), 0, stream, rel, meta, bucket);
    hipLaunchKernelGGL(k_scan,    dim3(1),    dim3(64),  0, stream, meta);
    hipLaunchKernelGGL(k_scatter, dim3(2344), dim3(256), 0, stream, rel, meta, bucket);
    hipLaunchKernelGGL(k_root,    dim3((N_NODES + 63) / 64), dim3(256), 0, stream, h, rw, bias, out);
    hipLaunchKernelGGL(k_edge,    dim3(N_EDGES / 64 + 8),    dim3(256), 0, stream, h, W, src, dst, meta, bucket, out);
    hipLaunchKernelGGL(k_relu,    dim3(N_NODES * FEAT / 4 / 256), dim3(256), 0, stream, out);
}

// Round 2
// 736.988 us; speedup vs baseline: 2.1777x; 2.1777x over previous
//
#include <hip/hip_runtime.h>

#define N_NODES 100000
#define N_EDGES 600000
#define FEAT 128
#define NUM_RELS 8
#define NUM_BASES 4
#define NB 2344              // ceil(N_EDGES / 256)
#define BUCKET_CAP 600512    // N_EDGES + 8*64 padding

// ws layout:
//   float W[8*128*128]   @ 0                 (512 KB) combined per-rel weights
//     (int blockhist[NB*8] overlaps W @ 0 — used only BEFORE k_build_w)
//   int   meta[32]       @ +131072 floats    [0..7]=cnt, [8..16]=bases(9)
//   int   bucket[600512] @ meta+32           edge ids grouped by relation, -1 = pad

// ---------- k_hist: per-block relation histogram (no global atomics); init bucket ----------
__global__ __launch_bounds__(256) void k_hist(const int* __restrict__ rel,
                                              int* __restrict__ blockhist,
                                              int* __restrict__ bucket) {
    __shared__ int hist[NUM_RELS];
    if (threadIdx.x < NUM_RELS) hist[threadIdx.x] = 0;
    __syncthreads();
    int i = blockIdx.x * 256 + threadIdx.x;
    if (i < BUCKET_CAP) bucket[i] = -1;
    if (i < N_EDGES) atomicAdd(&hist[rel[i]], 1);      // LDS atomic
    __syncthreads();
    if (blockIdx.x < NB && threadIdx.x < NUM_RELS)
        blockhist[blockIdx.x * NUM_RELS + threadIdx.x] = hist[threadIdx.x];
}

// ---------- k_scan1: one wave per relation — exclusive scan over per-block counts ----------
__global__ __launch_bounds__(64) void k_scan1(int* __restrict__ blockhist,
                                              int* __restrict__ meta) {
    int r = blockIdx.x;
    int lane = threadIdx.x;
    int carry = 0;
    for (int c = 0; c < (NB + 63) / 64; ++c) {
        int idx = c * 64 + lane;
        int v = (idx < NB) ? blockhist[idx * NUM_RELS + r] : 0;
        int incl = v;
#pragma unroll
        for (int d = 1; d < 64; d <<= 1) {
            int t = __shfl_up(incl, d);
            if (lane >= d) incl += t;
        }
        int ex = incl - v + carry;
        if (idx < NB) blockhist[idx * NUM_RELS + r] = ex;
        carry += __shfl(incl, 63);
    }
    if (lane == 0) meta[r] = carry;                    // per-rel total
}

// ---------- k_scan2: 64-padded relation bases ----------
__global__ void k_scan2(int* __restrict__ meta) {
    if (blockIdx.x == 0 && threadIdx.x == 0) {
        int acc = 0;
        for (int r = 0; r < NUM_RELS; ++r) {
            meta[8 + r] = acc;
            acc += ((meta[r] + 63) >> 6) << 6;
        }
        meta[16] = acc;                                // padded total
    }
}

// ---------- k_scatter_det: deterministic block offsets, LDS cursors only ----------
__global__ __launch_bounds__(256) void k_scatter_det(const int* __restrict__ rel,
                                                     const int* __restrict__ meta,
                                                     const int* __restrict__ blockhist,
                                                     int* __restrict__ bucket) {
    __shared__ int cur[NUM_RELS];
    int b = blockIdx.x;
    if (threadIdx.x < NUM_RELS)
        cur[threadIdx.x] = meta[8 + threadIdx.x] + blockhist[b * NUM_RELS + threadIdx.x];
    __syncthreads();
    int i = b * 256 + threadIdx.x;
    if (i < N_EDGES) {
        int r = rel[i];
        int pos = atomicAdd(&cur[r], 1);               // LDS atomic
        bucket[pos] = i;
    }
}

// ---------- k_build_w: W[r] = sum_b w_comp[r,b] * weight[b] ----------
__global__ __launch_bounds__(256) void k_build_w(const float* __restrict__ weight,
                                                 const float* __restrict__ w_comp,
                                                 float* __restrict__ W) {
    int idx = blockIdx.x * 256 + threadIdx.x;
    if (idx < NUM_RELS * FEAT * FEAT) {
        int r = idx >> 14;
        int e = idx & 16383;
        float acc = 0.f;
#pragma unroll
        for (int b = 0; b < NUM_BASES; ++b)
            acc += w_comp[r * NUM_BASES + b] * weight[b * FEAT * FEAT + e];
        W[idx] = acc;
    }
}

// ---------- k_root: out = h @ root_weight + bias (64 nodes/block, 16/wave) ----------
__global__ __launch_bounds__(256) void k_root(const float* __restrict__ h,
                                              const float* __restrict__ rw,
                                              const float* __restrict__ bias,
                                              float* __restrict__ out) {
    __shared__ float lds[FEAT * FEAT];                 // 64 KB
    const float4* rw4 = (const float4*)rw;
    float4* lds4 = (float4*)lds;
#pragma unroll
    for (int t = 0; t < 16; ++t)
        lds4[threadIdx.x + t * 256] = rw4[threadIdx.x + t * 256];
    __syncthreads();

    int wave = threadIdx.x >> 6, lane = threadIdx.x & 63;
    int n0 = blockIdx.x * 64 + wave * 16;

    float hreg[16][2];
#pragma unroll
    for (int e = 0; e < 16; ++e) {
        int n = n0 + e; if (n >= N_NODES) n = N_NODES - 1;
        hreg[e][0] = h[n * FEAT + lane];
        hreg[e][1] = h[n * FEAT + lane + 64];
    }
    float b0 = bias[lane], b1 = bias[lane + 64];
    float acc0[16], acc1[16];
#pragma unroll
    for (int e = 0; e < 16; ++e) { acc0[e] = b0; acc1[e] = b1; }

#pragma unroll
    for (int half = 0; half < 2; ++half) {
        for (int ii = 0; ii < 64; ++ii) {
            int i = half * 64 + ii;
            float w0 = lds[i * FEAT + lane];
            float w1 = lds[i * FEAT + lane + 64];
#pragma unroll
            for (int e = 0; e < 16; ++e) {
                float hv = __int_as_float(
                    __builtin_amdgcn_readlane(__float_as_int(hreg[e][half]), ii));
                acc0[e] += hv * w0;
                acc1[e] += hv * w1;
            }
        }
    }
#pragma unroll
    for (int e = 0; e < 16; ++e) {
        int n = n0 + e;
        if (n < N_NODES) {
            out[n * FEAT + lane]      = acc0[e];
            out[n * FEAT + lane + 64] = acc1[e];
        }
    }
}

// ---------- k_edge: per-relation edge GEMV + atomic scatter (64 edges/block) ----------
__global__ __launch_bounds__(256) void k_edge(const float* __restrict__ h,
                                              const float* __restrict__ W,
                                              const int* __restrict__ srcI,
                                              const int* __restrict__ dstI,
                                              const int* __restrict__ meta,
                                              const int* __restrict__ bucket,
                                              float* __restrict__ out) {
    __shared__ float lds[FEAT * FEAT];                 // 64 KB
    const int* bases = meta + 8;
    int ntot = bases[8];
    int p0 = blockIdx.x * 64;
    if (p0 >= ntot) return;                            // block-uniform exit

    int rel = 0;
#pragma unroll
    for (int r = 1; r < NUM_RELS; ++r) if (p0 >= bases[r]) rel = r;

    const float4* w4 = (const float4*)(W + rel * FEAT * FEAT);
    float4* lds4 = (float4*)lds;
#pragma unroll
    for (int t = 0; t < 16; ++t)
        lds4[threadIdx.x + t * 256] = w4[threadIdx.x + t * 256];
    __syncthreads();

    int wave = threadIdx.x >> 6, lane = threadIdx.x & 63;
    int p = p0 + wave * 16;

    int dstn[16];
    float hreg[16][2];
#pragma unroll
    for (int e = 0; e < 16; ++e) {
        int eid = bucket[p + e];
        int sn = 0;
        if (eid >= 0) { sn = srcI[eid]; dstn[e] = dstI[eid]; }
        else          { dstn[e] = -1; }
        hreg[e][0] = h[sn * FEAT + lane];
        hreg[e][1] = h[sn * FEAT + lane + 64];
    }

    float acc0[16], acc1[16];
#pragma unroll
    for (int e = 0; e < 16; ++e) { acc0[e] = 0.f; acc1[e] = 0.f; }

#pragma unroll
    for (int half = 0; half < 2; ++half) {
        for (int ii = 0; ii < 64; ++ii) {
            int i = half * 64 + ii;
            float w0 = lds[i * FEAT + lane];
            float w1 = lds[i * FEAT + lane + 64];
#pragma unroll
            for (int e = 0; e < 16; ++e) {
                float hv = __int_as_float(
                    __builtin_amdgcn_readlane(__float_as_int(hreg[e][half]), ii));
                acc0[e] += hv * w0;
                acc1[e] += hv * w1;
            }
        }
    }
#pragma unroll
    for (int e = 0; e < 16; ++e) {
        if (dstn[e] >= 0) {
            atomicAdd(&out[dstn[e] * FEAT + lane],      acc0[e]);
            atomicAdd(&out[dstn[e] * FEAT + lane + 64], acc1[e]);
        }
    }
}

// ---------- k_relu ----------
__global__ __launch_bounds__(256) void k_relu(float* __restrict__ out) {
    int i = blockIdx.x * 256 + threadIdx.x;
    if (i < N_NODES * FEAT / 4) {
        float4* o4 = (float4*)out;
        float4 v = o4[i];
        v.x = fmaxf(v.x, 0.f);
        v.y = fmaxf(v.y, 0.f);
        v.z = fmaxf(v.z, 0.f);
        v.w = fmaxf(v.w, 0.f);
        o4[i] = v;
    }
}

extern "C" void kernel_launch(void* const* d_in, const int* in_sizes, int n_in,
                              void* d_out, int out_size, void* d_ws, size_t ws_size,
                              hipStream_t stream) {
    const float* h    = (const float*)d_in[0];
    const float* wgt  = (const float*)d_in[1];
    const float* wcmp = (const float*)d_in[2];
    const float* rw   = (const float*)d_in[3];
    const float* bias = (const float*)d_in[4];
    const int*   src  = (const int*)d_in[5];
    const int*   dst  = (const int*)d_in[6];
    const int*   rel  = (const int*)d_in[7];
    float* out = (float*)d_out;

    float* W        = (float*)d_ws;
    int*   blockhist= (int*)d_ws;                        // overlaps W; dead after k_scatter_det
    int*   meta     = (int*)(W + NUM_RELS * FEAT * FEAT);
    int*   bucket   = meta + 32;

    // bucketing first (blockhist lives in the W region), then weights, then compute
    hipLaunchKernelGGL(k_hist,        dim3(2346), dim3(256), 0, stream, rel, blockhist, bucket);
    hipLaunchKernelGGL(k_scan1,       dim3(NUM_RELS), dim3(64), 0, stream, blockhist, meta);
    hipLaunchKernelGGL(k_scan2,       dim3(1),    dim3(64),  0, stream, meta);
    hipLaunchKernelGGL(k_scatter_det, dim3(NB),   dim3(256), 0, stream, rel, meta, blockhist, bucket);
    hipLaunchKernelGGL(k_build_w,     dim3(512),  dim3(256), 0, stream, wgt, wcmp, W);
    hipLaunchKernelGGL(k_root,        dim3((N_NODES + 63) / 64), dim3(256), 0, stream, h, rw, bias, out);
    hipLaunchKernelGGL(k_edge,        dim3(N_EDGES / 64 + 8),    dim3(256), 0, stream, h, W, src, dst, meta, bucket, out);
    hipLaunchKernelGGL(k_relu,        dim3(N_NODES * FEAT / 4 / 256), dim3(256), 0, stream, out);
}

// Round 3
// 431.096 us; speedup vs baseline: 3.7229x; 1.7096x over previous
//
#include <hip/hip_runtime.h>
#include <hip/hip_bf16.h>

#define N_NODES 100000
#define N_EDGES 600000
#define FEAT 128
#define NUM_RELS 8
#define NUM_BASES 4
#define NB 2344                          // ceil(N_EDGES/256)
#define PAD 128                          // relation region padding (block tile)
#define BUCKET_CAP (N_EDGES + NUM_RELS * PAD)   // 601024

typedef short bf16x8 __attribute__((ext_vector_type(8)));
typedef float f32x4  __attribute__((ext_vector_type(4)));

__device__ inline short f2bf(float x) {
    __hip_bfloat16 b = __float2bfloat16(x);
    return *reinterpret_cast<short*>(&b);
}

// ws layout (bytes):
//   short Wt[9*128*128]   @ 0          294912 B  (8 rels + root, TRANSPOSED [out][in], bf16)
//   short hb[N*128]       @ 294912     25.6 MB   (h cast to bf16)
//   int   meta[32]        @ 25894912   [0..7]=cnt, [8..16]=bases(9)
//   int   bucket[601024]  @ +128
//   int   blockhist[NB*8] @ after bucket

// ---------- cast h -> bf16 ----------
__global__ __launch_bounds__(256) void k_cast_h(const float* __restrict__ h,
                                                short* __restrict__ hb) {
    int i = blockIdx.x * 256 + threadIdx.x;
    if (i < N_NODES * FEAT / 8) {
        const float4* h4 = (const float4*)h;
        float4 v0 = h4[2 * i], v1 = h4[2 * i + 1];
        union { short s[8]; bf16x8 v; } u;
        u.s[0] = f2bf(v0.x); u.s[1] = f2bf(v0.y); u.s[2] = f2bf(v0.z); u.s[3] = f2bf(v0.w);
        u.s[4] = f2bf(v1.x); u.s[5] = f2bf(v1.y); u.s[6] = f2bf(v1.z); u.s[7] = f2bf(v1.w);
        ((bf16x8*)hb)[i] = u.v;
    }
}

// ---------- per-block relation histogram; init bucket ----------
__global__ __launch_bounds__(256) void k_hist(const int* __restrict__ rel,
                                              int* __restrict__ blockhist,
                                              int* __restrict__ bucket) {
    __shared__ int hist[NUM_RELS];
    if (threadIdx.x < NUM_RELS) hist[threadIdx.x] = 0;
    __syncthreads();
    int i = blockIdx.x * 256 + threadIdx.x;
    if (i < BUCKET_CAP) bucket[i] = -1;
    if (i < N_EDGES) atomicAdd(&hist[rel[i]], 1);      // LDS atomic
    __syncthreads();
    if (blockIdx.x < NB && threadIdx.x < NUM_RELS)
        blockhist[blockIdx.x * NUM_RELS + threadIdx.x] = hist[threadIdx.x];
}

// ---------- one wave per relation: exclusive scan over per-block counts ----------
__global__ __launch_bounds__(64) void k_scan1(int* __restrict__ blockhist,
                                              int* __restrict__ meta) {
    int r = blockIdx.x;
    int lane = threadIdx.x;
    int carry = 0;
    for (int c = 0; c < (NB + 63) / 64; ++c) {
        int idx = c * 64 + lane;
        int v = (idx < NB) ? blockhist[idx * NUM_RELS + r] : 0;
        int incl = v;
#pragma unroll
        for (int d = 1; d < 64; d <<= 1) {
            int t = __shfl_up(incl, d);
            if (lane >= d) incl += t;
        }
        int ex = incl - v + carry;
        if (idx < NB) blockhist[idx * NUM_RELS + r] = ex;
        carry += __shfl(incl, 63);
    }
    if (lane == 0) meta[r] = carry;
}

// ---------- 128-padded relation bases ----------
__global__ void k_scan2(int* __restrict__ meta) {
    if (blockIdx.x == 0 && threadIdx.x == 0) {
        int acc = 0;
        for (int r = 0; r < NUM_RELS; ++r) {
            meta[8 + r] = acc;
            acc += ((meta[r] + PAD - 1) / PAD) * PAD;
        }
        meta[16] = acc;
    }
}

// ---------- deterministic scatter: LDS cursors only ----------
__global__ __launch_bounds__(256) void k_scatter_det(const int* __restrict__ rel,
                                                     const int* __restrict__ meta,
                                                     const int* __restrict__ blockhist,
                                                     int* __restrict__ bucket) {
    __shared__ int cur[NUM_RELS];
    int b = blockIdx.x;
    if (threadIdx.x < NUM_RELS)
        cur[threadIdx.x] = meta[8 + threadIdx.x] + blockhist[b * NUM_RELS + threadIdx.x];
    __syncthreads();
    int i = b * 256 + threadIdx.x;
    if (i < N_EDGES) {
        int r = rel[i];
        int pos = atomicAdd(&cur[r], 1);               // LDS atomic
        bucket[pos] = i;
    }
}

// ---------- build bf16 TRANSPOSED weights: Wt[r][o][i]; slot 8 = root_weight ----------
__global__ __launch_bounds__(256) void k_build_wt(const float* __restrict__ weight,
                                                  const float* __restrict__ w_comp,
                                                  const float* __restrict__ rw,
                                                  short* __restrict__ Wt) {
    int idx = blockIdx.x * 256 + threadIdx.x;
    if (idx < 9 * FEAT * FEAT) {
        int r = idx >> 14;
        int e = idx & 16383;
        int i = e >> 7, o = e & 127;
        float acc;
        if (r < NUM_RELS) {
            acc = 0.f;
#pragma unroll
            for (int b = 0; b < NUM_BASES; ++b)
                acc += w_comp[r * NUM_BASES + b] * weight[b * FEAT * FEAT + e];
        } else {
            acc = rw[e];
        }
        Wt[(r << 14) + (o << 7) + i] = f2bf(acc);
    }
}

// ---------- root GEMM via MFMA: out = h @ root_weight + bias ----------
__global__ __launch_bounds__(256) void k_root_mfma(const short* __restrict__ hb,
                                                   const short* __restrict__ Wt,
                                                   const float* __restrict__ bias,
                                                   float* __restrict__ out) {
    __shared__ short lds[FEAT * FEAT];                  // 32 KB bf16
    const float4* s4 = (const float4*)(Wt + 8 * FEAT * FEAT);
    float4* l4 = (float4*)lds;
#pragma unroll
    for (int t = 0; t < 8; ++t)
        l4[threadIdx.x + t * 256] = s4[threadIdx.x + t * 256];
    __syncthreads();

    int wave = threadIdx.x >> 6, lane = threadIdx.x & 63;
    int quad = lane >> 4, n16 = lane & 15;
    int base = blockIdx.x * 128 + wave * 32;

    int rowA0 = base + n16;        if (rowA0 >= N_NODES) rowA0 = N_NODES - 1;
    int rowA1 = base + 16 + n16;   if (rowA1 >= N_NODES) rowA1 = N_NODES - 1;

    f32x4 acc[2][8];
#pragma unroll
    for (int mt = 0; mt < 2; ++mt)
#pragma unroll
        for (int nt = 0; nt < 8; ++nt) acc[mt][nt] = (f32x4)0.f;

    const bf16x8* a0p = (const bf16x8*)(hb + rowA0 * FEAT);
    const bf16x8* a1p = (const bf16x8*)(hb + rowA1 * FEAT);
    const bf16x8* bp  = (const bf16x8*)lds;
#pragma unroll
    for (int ks = 0; ks < 4; ++ks) {
        bf16x8 a0 = a0p[ks * 4 + quad];
        bf16x8 a1 = a1p[ks * 4 + quad];
#pragma unroll
        for (int nt = 0; nt < 8; ++nt) {
            bf16x8 b = bp[(nt * 16 + n16) * 16 + ks * 4 + quad];
            acc[0][nt] = __builtin_amdgcn_mfma_f32_16x16x32_bf16(a0, b, acc[0][nt], 0, 0, 0);
            acc[1][nt] = __builtin_amdgcn_mfma_f32_16x16x32_bf16(a1, b, acc[1][nt], 0, 0, 0);
        }
    }

    float bv[8];
#pragma unroll
    for (int nt = 0; nt < 8; ++nt) bv[nt] = bias[nt * 16 + n16];

#pragma unroll
    for (int mt = 0; mt < 2; ++mt)
#pragma unroll
        for (int nt = 0; nt < 8; ++nt) {
            int col = nt * 16 + n16;
#pragma unroll
            for (int reg = 0; reg < 4; ++reg) {
                int node = base + mt * 16 + quad * 4 + reg;
                if (node < N_NODES) out[node * FEAT + col] = acc[mt][nt][reg] + bv[nt];
            }
        }
}

// ---------- edge GEMM via MFMA + atomic scatter (128 positions/block) ----------
__global__ __launch_bounds__(256) void k_edge_mfma(const short* __restrict__ hb,
                                                   const short* __restrict__ Wt,
                                                   const int* __restrict__ srcI,
                                                   const int* __restrict__ dstI,
                                                   const int* __restrict__ meta,
                                                   const int* __restrict__ bucket,
                                                   float* __restrict__ out) {
    __shared__ short lds[FEAT * FEAT];                  // 32 KB bf16
    const int* bases = meta + 8;
    int ntot = bases[8];
    int p0 = blockIdx.x * 128;
    if (p0 >= ntot) return;                             // block-uniform exit

    int rel = 0;
#pragma unroll
    for (int r = 1; r < NUM_RELS; ++r) if (p0 >= bases[r]) rel = r;

    const float4* s4 = (const float4*)(Wt + rel * FEAT * FEAT);
    float4* l4 = (float4*)lds;
#pragma unroll
    for (int t = 0; t < 8; ++t)
        l4[threadIdx.x + t * 256] = s4[threadIdx.x + t * 256];
    __syncthreads();

    int wave = threadIdx.x >> 6, lane = threadIdx.x & 63;
    int quad = lane >> 4, n16 = lane & 15;
    int pb = p0 + wave * 32;

    // A-fragment source rows (per lane: edge = pb + mt*16 + n16)
    int src0 = 0, src1 = 0;
    { int e0 = bucket[pb + n16];      if (e0 >= 0) src0 = srcI[e0];
      int e1 = bucket[pb + 16 + n16]; if (e1 >= 0) src1 = srcI[e1]; }

    // C-row destinations (per lane: rows quad*4+reg of each m-tile)
    int dstv[2][4];
#pragma unroll
    for (int mt = 0; mt < 2; ++mt)
#pragma unroll
        for (int reg = 0; reg < 4; ++reg) {
            int e = bucket[pb + mt * 16 + quad * 4 + reg];
            dstv[mt][reg] = (e >= 0) ? dstI[e] : -1;
        }

    f32x4 acc[2][8];
#pragma unroll
    for (int mt = 0; mt < 2; ++mt)
#pragma unroll
        for (int nt = 0; nt < 8; ++nt) acc[mt][nt] = (f32x4)0.f;

    const bf16x8* a0p = (const bf16x8*)(hb + src0 * FEAT);
    const bf16x8* a1p = (const bf16x8*)(hb + src1 * FEAT);
    const bf16x8* bp  = (const bf16x8*)lds;
#pragma unroll
    for (int ks = 0; ks < 4; ++ks) {
        bf16x8 a0 = a0p[ks * 4 + quad];
        bf16x8 a1 = a1p[ks * 4 + quad];
#pragma unroll
        for (int nt = 0; nt < 8; ++nt) {
            bf16x8 b = bp[(nt * 16 + n16) * 16 + ks * 4 + quad];
            acc[0][nt] = __builtin_amdgcn_mfma_f32_16x16x32_bf16(a0, b, acc[0][nt], 0, 0, 0);
            acc[1][nt] = __builtin_amdgcn_mfma_f32_16x16x32_bf16(a1, b, acc[1][nt], 0, 0, 0);
        }
    }

#pragma unroll
    for (int mt = 0; mt < 2; ++mt)
#pragma unroll
        for (int nt = 0; nt < 8; ++nt) {
            int col = nt * 16 + n16;
#pragma unroll
            for (int reg = 0; reg < 4; ++reg) {
                int d = dstv[mt][reg];
                if (d >= 0) atomicAdd(&out[d * FEAT + col], acc[mt][nt][reg]);
            }
        }
}

// ---------- relu ----------
__global__ __launch_bounds__(256) void k_relu(float* __restrict__ out) {
    int i = blockIdx.x * 256 + threadIdx.x;
    if (i < N_NODES * FEAT / 4) {
        float4* o4 = (float4*)out;
        float4 v = o4[i];
        v.x = fmaxf(v.x, 0.f);
        v.y = fmaxf(v.y, 0.f);
        v.z = fmaxf(v.z, 0.f);
        v.w = fmaxf(v.w, 0.f);
        o4[i] = v;
    }
}

extern "C" void kernel_launch(void* const* d_in, const int* in_sizes, int n_in,
                              void* d_out, int out_size, void* d_ws, size_t ws_size,
                              hipStream_t stream) {
    const float* h    = (const float*)d_in[0];
    const float* wgt  = (const float*)d_in[1];
    const float* wcmp = (const float*)d_in[2];
    const float* rw   = (const float*)d_in[3];
    const float* bias = (const float*)d_in[4];
    const int*   src  = (const int*)d_in[5];
    const int*   dst  = (const int*)d_in[6];
    const int*   rel  = (const int*)d_in[7];
    float* out = (float*)d_out;

    char* ws = (char*)d_ws;
    short* Wt        = (short*)ws;                         // 294912 B
    short* hb        = (short*)(ws + 294912);              // 25.6 MB
    int*   meta      = (int*)(ws + 25894912);
    int*   bucket    = meta + 32;
    int*   blockhist = bucket + BUCKET_CAP;

    hipLaunchKernelGGL(k_cast_h,      dim3(6250), dim3(256), 0, stream, h, hb);
    hipLaunchKernelGGL(k_hist,        dim3(2348), dim3(256), 0, stream, rel, blockhist, bucket);
    hipLaunchKernelGGL(k_scan1,       dim3(NUM_RELS), dim3(64), 0, stream, blockhist, meta);
    hipLaunchKernelGGL(k_scan2,       dim3(1),    dim3(64),  0, stream, meta);
    hipLaunchKernelGGL(k_scatter_det, dim3(NB),   dim3(256), 0, stream, rel, meta, blockhist, bucket);
    hipLaunchKernelGGL(k_build_wt,    dim3(576),  dim3(256), 0, stream, wgt, wcmp, rw, Wt);
    hipLaunchKernelGGL(k_root_mfma,   dim3((N_NODES + 127) / 128), dim3(256), 0, stream, hb, Wt, bias, out);
    hipLaunchKernelGGL(k_edge_mfma,   dim3(BUCKET_CAP / 128),      dim3(256), 0, stream, hb, Wt, src, dst, meta, bucket, out);
    hipLaunchKernelGGL(k_relu,        dim3(N_NODES * FEAT / 4 / 256), dim3(256), 0, stream, out);
}

// Round 4
// 420.554 us; speedup vs baseline: 3.8163x; 1.0251x over previous
//
#include <hip/hip_runtime.h>
#include <hip/hip_bf16.h>

#define N_NODES 100000
#define N_EDGES 600000
#define FEAT 128
#define NUM_RELS 8
#define NUM_BASES 4
#define NB 2344                          // ceil(N_EDGES/256)
#define PAD 128                          // relation region padding (block tile)
#define BUCKET_CAP (N_EDGES + NUM_RELS * PAD)   // 601024
#define NB1 391                          // ceil(N_NODES/256)

typedef short bf16x8 __attribute__((ext_vector_type(8)));
typedef float f32x4  __attribute__((ext_vector_type(4)));

__device__ inline short f2bf(float x) {
    __hip_bfloat16 b = __float2bfloat16(x);
    return *reinterpret_cast<short*>(&b);
}

// ============================ common prep ============================

__global__ __launch_bounds__(256) void k_cast_h(const float* __restrict__ h,
                                                short* __restrict__ hb) {
    int i = blockIdx.x * 256 + threadIdx.x;
    if (i < N_NODES * FEAT / 8) {
        const float4* h4 = (const float4*)h;
        float4 v0 = h4[2 * i], v1 = h4[2 * i + 1];
        union { short s[8]; bf16x8 v; } u;
        u.s[0] = f2bf(v0.x); u.s[1] = f2bf(v0.y); u.s[2] = f2bf(v0.z); u.s[3] = f2bf(v0.w);
        u.s[4] = f2bf(v1.x); u.s[5] = f2bf(v1.y); u.s[6] = f2bf(v1.z); u.s[7] = f2bf(v1.w);
        ((bf16x8*)hb)[i] = u.v;
    }
}

// per-block relation histogram; init bucket (and slot2dpos if provided)
__global__ __launch_bounds__(256) void k_hist(const int* __restrict__ rel,
                                              int* __restrict__ blockhist,
                                              int* __restrict__ bucket,
                                              int* __restrict__ s2d) {
    __shared__ int hist[NUM_RELS];
    if (threadIdx.x < NUM_RELS) hist[threadIdx.x] = 0;
    __syncthreads();
    int i = blockIdx.x * 256 + threadIdx.x;
    if (i < BUCKET_CAP) {
        bucket[i] = -1;
        if (s2d) s2d[i] = -1;
    }
    if (i < N_EDGES) atomicAdd(&hist[rel[i]], 1);      // LDS atomic
    __syncthreads();
    if (blockIdx.x < NB && threadIdx.x < NUM_RELS)
        blockhist[blockIdx.x * NUM_RELS + threadIdx.x] = hist[threadIdx.x];
}

__global__ __launch_bounds__(64) void k_scan1(int* __restrict__ blockhist,
                                              int* __restrict__ meta) {
    int r = blockIdx.x;
    int lane = threadIdx.x;
    int carry = 0;
    for (int c = 0; c < (NB + 63) / 64; ++c) {
        int idx = c * 64 + lane;
        int v = (idx < NB) ? blockhist[idx * NUM_RELS + r] : 0;
        int incl = v;
#pragma unroll
        for (int d = 1; d < 64; d <<= 1) {
            int t = __shfl_up(incl, d);
            if (lane >= d) incl += t;
        }
        int ex = incl - v + carry;
        if (idx < NB) blockhist[idx * NUM_RELS + r] = ex;
        carry += __shfl(incl, 63);
    }
    if (lane == 0) meta[r] = carry;
}

__global__ void k_scan2(int* __restrict__ meta) {
    if (blockIdx.x == 0 && threadIdx.x == 0) {
        int acc = 0;
        for (int r = 0; r < NUM_RELS; ++r) {
            meta[8 + r] = acc;
            acc += ((meta[r] + PAD - 1) / PAD) * PAD;
        }
        meta[16] = acc;
    }
}

// deterministic scatter into relation buckets; optionally record inverse map
__global__ __launch_bounds__(256) void k_scatter_det(const int* __restrict__ rel,
                                                     const int* __restrict__ meta,
                                                     const int* __restrict__ blockhist,
                                                     int* __restrict__ bucket,
                                                     int* __restrict__ inv) {
    __shared__ int cur[NUM_RELS];
    int b = blockIdx.x;
    if (threadIdx.x < NUM_RELS)
        cur[threadIdx.x] = meta[8 + threadIdx.x] + blockhist[b * NUM_RELS + threadIdx.x];
    __syncthreads();
    int i = b * 256 + threadIdx.x;
    if (i < N_EDGES) {
        int r = rel[i];
        int pos = atomicAdd(&cur[r], 1);               // LDS atomic
        bucket[pos] = i;
        if (inv) inv[i] = pos;
    }
}

__global__ __launch_bounds__(256) void k_build_wt(const float* __restrict__ weight,
                                                  const float* __restrict__ w_comp,
                                                  const float* __restrict__ rw,
                                                  short* __restrict__ Wt) {
    int idx = blockIdx.x * 256 + threadIdx.x;
    if (idx < 9 * FEAT * FEAT) {
        int r = idx >> 14;
        int e = idx & 16383;
        int i = e >> 7, o = e & 127;
        float acc;
        if (r < NUM_RELS) {
            acc = 0.f;
#pragma unroll
            for (int b = 0; b < NUM_BASES; ++b)
                acc += w_comp[r * NUM_BASES + b] * weight[b * FEAT * FEAT + e];
        } else {
            acc = rw[e];
        }
        Wt[(r << 14) + (o << 7) + i] = f2bf(acc);
    }
}

// ============================ dst counting-sort ============================

__global__ __launch_bounds__(256) void k_zero(int* __restrict__ cnt) {
    int i = blockIdx.x * 256 + threadIdx.x;
    if (i < N_NODES) cnt[i] = 0;
}

__global__ __launch_bounds__(256) void k_hist_dst(const int* __restrict__ dst,
                                                  int* __restrict__ cnt) {
    int i = blockIdx.x * 256 + threadIdx.x;
    if (i < N_EDGES) atomicAdd(&cnt[dst[i]], 1);       // 100K bins, ~6/bin
}

__global__ __launch_bounds__(256) void k_s1(const int* __restrict__ cnt,
                                            int* __restrict__ bsum) {
    int i = blockIdx.x * 256 + threadIdx.x;
    int v = (i < N_NODES) ? cnt[i] : 0;
#pragma unroll
    for (int d = 32; d; d >>= 1) v += __shfl_down(v, d);
    __shared__ int ws4[4];
    if ((threadIdx.x & 63) == 0) ws4[threadIdx.x >> 6] = v;
    __syncthreads();
    if (threadIdx.x == 0) bsum[blockIdx.x] = ws4[0] + ws4[1] + ws4[2] + ws4[3];
}

__global__ void k_s2(const int* __restrict__ bsum,
                     int* __restrict__ bbase,
                     int* __restrict__ offs) {
    if (blockIdx.x == 0 && threadIdx.x == 0) {
        int acc = 0;
        for (int b = 0; b < NB1; ++b) { bbase[b] = acc; acc += bsum[b]; }
        offs[N_NODES] = acc;                           // == N_EDGES
    }
}

__global__ __launch_bounds__(256) void k_s3(const int* __restrict__ cnt,
                                            const int* __restrict__ bbase,
                                            int* __restrict__ offs,
                                            int* __restrict__ cursor) {
    int i = blockIdx.x * 256 + threadIdx.x;
    int lane = threadIdx.x & 63, wid = threadIdx.x >> 6;
    int v = (i < N_NODES) ? cnt[i] : 0;
    int incl = v;
#pragma unroll
    for (int d = 1; d < 64; d <<= 1) {
        int t = __shfl_up(incl, d);
        if (lane >= d) incl += t;
    }
    __shared__ int wsum[4];
    if (lane == 63) wsum[wid] = incl;
    __syncthreads();
    if (threadIdx.x == 0) {
        int a = 0;
#pragma unroll
        for (int w = 0; w < 4; ++w) { int x = wsum[w]; wsum[w] = a; a += x; }
    }
    __syncthreads();
    int ex = incl - v + wsum[wid] + bbase[blockIdx.x];
    if (i < N_NODES) { offs[i] = ex; cursor[i] = ex; }
}

// relation-slot -> dst-sorted position
__global__ __launch_bounds__(256) void k_scatter_dst(const int* __restrict__ dst,
                                                     const int* __restrict__ inv,
                                                     int* __restrict__ cursor,
                                                     int* __restrict__ s2d) {
    int e = blockIdx.x * 256 + threadIdx.x;
    if (e < N_EDGES) {
        int p = atomicAdd(&cursor[dst[e]], 1);         // ~6-way contention
        s2d[inv[e]] = p;
    }
}

// ============================ MFMA GEMMs ============================
// LDS layout: row o (out-col) holds 16 bf16x8 chunks along input dim,
// chunk c stored at (o<<4) + ((c+o)&15)  — bank-conflict-free swizzle.

__global__ __launch_bounds__(256) void k_root_mfma(const short* __restrict__ hb,
                                                   const short* __restrict__ Wt,
                                                   const float* __restrict__ bias,
                                                   float* __restrict__ out) {
    __shared__ short lds[FEAT * FEAT];                  // 32 KB bf16
    const float4* s4 = (const float4*)(Wt + 8 * FEAT * FEAT);
    float4* l4 = (float4*)lds;
#pragma unroll
    for (int t = 0; t < 8; ++t) {
        int linear = threadIdx.x + t * 256;
        int o = linear >> 4, c = linear & 15;
        l4[(o << 4) + ((c + o) & 15)] = s4[linear];
    }
    __syncthreads();

    int wave = threadIdx.x >> 6, lane = threadIdx.x & 63;
    int quad = lane >> 4, n16 = lane & 15;
    int base = blockIdx.x * 128 + wave * 32;

    int rowA0 = base + n16;        if (rowA0 >= N_NODES) rowA0 = N_NODES - 1;
    int rowA1 = base + 16 + n16;   if (rowA1 >= N_NODES) rowA1 = N_NODES - 1;

    f32x4 acc[2][8];
#pragma unroll
    for (int mt = 0; mt < 2; ++mt)
#pragma unroll
        for (int nt = 0; nt < 8; ++nt) acc[mt][nt] = (f32x4)0.f;

    const bf16x8* a0p = (const bf16x8*)(hb + rowA0 * FEAT);
    const bf16x8* a1p = (const bf16x8*)(hb + rowA1 * FEAT);
    const bf16x8* bp  = (const bf16x8*)lds;
#pragma unroll
    for (int ks = 0; ks < 4; ++ks) {
        bf16x8 a0 = a0p[ks * 4 + quad];
        bf16x8 a1 = a1p[ks * 4 + quad];
        int sw = (ks * 4 + quad + n16) & 15;
#pragma unroll
        for (int nt = 0; nt < 8; ++nt) {
            bf16x8 b = bp[((nt * 16 + n16) << 4) + sw];
            acc[0][nt] = __builtin_amdgcn_mfma_f32_16x16x32_bf16(a0, b, acc[0][nt], 0, 0, 0);
            acc[1][nt] = __builtin_amdgcn_mfma_f32_16x16x32_bf16(a1, b, acc[1][nt], 0, 0, 0);
        }
    }

    float bv[8];
#pragma unroll
    for (int nt = 0; nt < 8; ++nt) bv[nt] = bias[nt * 16 + n16];

#pragma unroll
    for (int mt = 0; mt < 2; ++mt)
#pragma unroll
        for (int nt = 0; nt < 8; ++nt) {
            int col = nt * 16 + n16;
#pragma unroll
            for (int reg = 0; reg < 4; ++reg) {
                int node = base + mt * 16 + quad * 4 + reg;
                if (node < N_NODES) out[node * FEAT + col] = acc[mt][nt][reg] + bv[nt];
            }
        }
}

// phase A (big-ws): edge GEMM -> plain stores into dst-sorted msg buffer
__global__ __launch_bounds__(256) void k_edge_msg(const short* __restrict__ hb,
                                                  const short* __restrict__ Wt,
                                                  const int* __restrict__ srcI,
                                                  const int* __restrict__ meta,
                                                  const int* __restrict__ bucket,
                                                  const int* __restrict__ s2d,
                                                  float* __restrict__ msgd) {
    __shared__ short lds[FEAT * FEAT];
    const int* bases = meta + 8;
    int ntot = bases[8];
    int p0 = blockIdx.x * 128;
    if (p0 >= ntot) return;

    int rel = 0;
#pragma unroll
    for (int r = 1; r < NUM_RELS; ++r) if (p0 >= bases[r]) rel = r;

    const float4* s4 = (const float4*)(Wt + rel * FEAT * FEAT);
    float4* l4 = (float4*)lds;
#pragma unroll
    for (int t = 0; t < 8; ++t) {
        int linear = threadIdx.x + t * 256;
        int o = linear >> 4, c = linear & 15;
        l4[(o << 4) + ((c + o) & 15)] = s4[linear];
    }
    __syncthreads();

    int wave = threadIdx.x >> 6, lane = threadIdx.x & 63;
    int quad = lane >> 4, n16 = lane & 15;
    int pb = p0 + wave * 32;

    int src0 = 0, src1 = 0;
    { int e0 = bucket[pb + n16];      if (e0 >= 0) src0 = srcI[e0];
      int e1 = bucket[pb + 16 + n16]; if (e1 >= 0) src1 = srcI[e1]; }

    int p8[2][4];
#pragma unroll
    for (int mt = 0; mt < 2; ++mt)
#pragma unroll
        for (int reg = 0; reg < 4; ++reg)
            p8[mt][reg] = s2d[pb + mt * 16 + quad * 4 + reg];

    f32x4 acc[2][8];
#pragma unroll
    for (int mt = 0; mt < 2; ++mt)
#pragma unroll
        for (int nt = 0; nt < 8; ++nt) acc[mt][nt] = (f32x4)0.f;

    const bf16x8* a0p = (const bf16x8*)(hb + src0 * FEAT);
    const bf16x8* a1p = (const bf16x8*)(hb + src1 * FEAT);
    const bf16x8* bp  = (const bf16x8*)lds;
#pragma unroll
    for (int ks = 0; ks < 4; ++ks) {
        bf16x8 a0 = a0p[ks * 4 + quad];
        bf16x8 a1 = a1p[ks * 4 + quad];
        int sw = (ks * 4 + quad + n16) & 15;
#pragma unroll
        for (int nt = 0; nt < 8; ++nt) {
            bf16x8 b = bp[((nt * 16 + n16) << 4) + sw];
            acc[0][nt] = __builtin_amdgcn_mfma_f32_16x16x32_bf16(a0, b, acc[0][nt], 0, 0, 0);
            acc[1][nt] = __builtin_amdgcn_mfma_f32_16x16x32_bf16(a1, b, acc[1][nt], 0, 0, 0);
        }
    }

#pragma unroll
    for (int mt = 0; mt < 2; ++mt)
#pragma unroll
        for (int reg = 0; reg < 4; ++reg) {
            int p = p8[mt][reg];
            if (p >= 0) {
                float* row = msgd + (size_t)p * FEAT + n16;
#pragma unroll
                for (int nt = 0; nt < 8; ++nt)
                    row[nt * 16] = acc[mt][nt][reg];
            }
        }
}

// phase B: one wave per dst — contiguous message run + root + relu
__global__ __launch_bounds__(256) void k_gather_dst(const int* __restrict__ offs,
                                                    const float* __restrict__ msgd,
                                                    float* __restrict__ out) {
    int wid = threadIdx.x >> 6, lane = threadIdx.x & 63;
    int d = blockIdx.x * 4 + wid;
    if (d >= N_NODES) return;
    int s = offs[d], e = offs[d + 1];
    float a0 = out[d * FEAT + lane];
    float a1 = out[d * FEAT + 64 + lane];
    for (int i = s; i < e; ++i) {
        a0 += msgd[(size_t)i * FEAT + lane];
        a1 += msgd[(size_t)i * FEAT + 64 + lane];
    }
    out[d * FEAT + lane]      = fmaxf(a0, 0.f);
    out[d * FEAT + 64 + lane] = fmaxf(a1, 0.f);
}

// ============================ fallback (small ws): atomic scatter ============================

__global__ __launch_bounds__(256) void k_edge_atomic(const short* __restrict__ hb,
                                                     const short* __restrict__ Wt,
                                                     const int* __restrict__ srcI,
                                                     const int* __restrict__ dstI,
                                                     const int* __restrict__ meta,
                                                     const int* __restrict__ bucket,
                                                     float* __restrict__ out) {
    __shared__ short lds[FEAT * FEAT];
    const int* bases = meta + 8;
    int ntot = bases[8];
    int p0 = blockIdx.x * 128;
    if (p0 >= ntot) return;

    int rel = 0;
#pragma unroll
    for (int r = 1; r < NUM_RELS; ++r) if (p0 >= bases[r]) rel = r;

    const float4* s4 = (const float4*)(Wt + rel * FEAT * FEAT);
    float4* l4 = (float4*)lds;
#pragma unroll
    for (int t = 0; t < 8; ++t) {
        int linear = threadIdx.x + t * 256;
        int o = linear >> 4, c = linear & 15;
        l4[(o << 4) + ((c + o) & 15)] = s4[linear];
    }
    __syncthreads();

    int wave = threadIdx.x >> 6, lane = threadIdx.x & 63;
    int quad = lane >> 4, n16 = lane & 15;
    int pb = p0 + wave * 32;

    int src0 = 0, src1 = 0;
    { int e0 = bucket[pb + n16];      if (e0 >= 0) src0 = srcI[e0];
      int e1 = bucket[pb + 16 + n16]; if (e1 >= 0) src1 = srcI[e1]; }

    int dstv[2][4];
#pragma unroll
    for (int mt = 0; mt < 2; ++mt)
#pragma unroll
        for (int reg = 0; reg < 4; ++reg) {
            int e = bucket[pb + mt * 16 + quad * 4 + reg];
            dstv[mt][reg] = (e >= 0) ? dstI[e] : -1;
        }

    f32x4 acc[2][8];
#pragma unroll
    for (int mt = 0; mt < 2; ++mt)
#pragma unroll
        for (int nt = 0; nt < 8; ++nt) acc[mt][nt] = (f32x4)0.f;

    const bf16x8* a0p = (const bf16x8*)(hb + src0 * FEAT);
    const bf16x8* a1p = (const bf16x8*)(hb + src1 * FEAT);
    const bf16x8* bp  = (const bf16x8*)lds;
#pragma unroll
    for (int ks = 0; ks < 4; ++ks) {
        bf16x8 a0 = a0p[ks * 4 + quad];
        bf16x8 a1 = a1p[ks * 4 + quad];
        int sw = (ks * 4 + quad + n16) & 15;
#pragma unroll
        for (int nt = 0; nt < 8; ++nt) {
            bf16x8 b = bp[((nt * 16 + n16) << 4) + sw];
            acc[0][nt] = __builtin_amdgcn_mfma_f32_16x16x32_bf16(a0, b, acc[0][nt], 0, 0, 0);
            acc[1][nt] = __builtin_amdgcn_mfma_f32_16x16x32_bf16(a1, b, acc[1][nt], 0, 0, 0);
        }
    }

#pragma unroll
    for (int mt = 0; mt < 2; ++mt)
#pragma unroll
        for (int nt = 0; nt < 8; ++nt) {
            int col = nt * 16 + n16;
#pragma unroll
            for (int reg = 0; reg < 4; ++reg) {
                int d = dstv[mt][reg];
                if (d >= 0) atomicAdd(&out[d * FEAT + col], acc[mt][nt][reg]);
            }
        }
}

__global__ __launch_bounds__(256) void k_relu(float* __restrict__ out) {
    int i = blockIdx.x * 256 + threadIdx.x;
    if (i < N_NODES * FEAT / 4) {
        float4* o4 = (float4*)out;
        float4 v = o4[i];
        v.x = fmaxf(v.x, 0.f);
        v.y = fmaxf(v.y, 0.f);
        v.z = fmaxf(v.z, 0.f);
        v.w = fmaxf(v.w, 0.f);
        o4[i] = v;
    }
}

// ============================ launch ============================

extern "C" void kernel_launch(void* const* d_in, const int* in_sizes, int n_in,
                              void* d_out, int out_size, void* d_ws, size_t ws_size,
                              hipStream_t stream) {
    const float* h    = (const float*)d_in[0];
    const float* wgt  = (const float*)d_in[1];
    const float* wcmp = (const float*)d_in[2];
    const float* rw   = (const float*)d_in[3];
    const float* bias = (const float*)d_in[4];
    const int*   src  = (const int*)d_in[5];
    const int*   dst  = (const int*)d_in[6];
    const int*   rel  = (const int*)d_in[7];
    float* out = (float*)d_out;

    char* ws = (char*)d_ws;
    short* Wt        = (short*)(ws + 0);            // 294,912 B
    short* hb        = (short*)(ws + 294912);       // 25.6 MB
    int*   meta      = (int*)(ws + 25894912);       // 128 B
    int*   bucket    = (int*)(ws + 25895040);       // 2,404,096 B
    int*   blockhist = (int*)(ws + 28299136);       // 75,008 B
    int*   inv       = (int*)(ws + 28374144);       // 2.4 MB
    int*   cnt       = (int*)(ws + 30774144);       // 400 KB
    int*   offs      = (int*)(ws + 31174144);       // 400,004 B (+pad)
    int*   cursor    = (int*)(ws + 31574272);       // 400 KB
    int*   bsum      = (int*)(ws + 31974272);       // 1,564 B (+pad)
    int*   bbase     = (int*)(ws + 31975936);       // 1,564 B (+pad)
    int*   s2d       = (int*)(ws + 31977600);       // 2,404,096 B
    float* msgd      = (float*)(ws + 34381696);     // 307.2 MB
    const size_t NEED = 34381696ull + (size_t)N_EDGES * FEAT * 4ull;  // ~342 MB
    const bool big = (ws_size >= NEED);

    hipLaunchKernelGGL(k_cast_h,  dim3(6250), dim3(256), 0, stream, h, hb);
    hipLaunchKernelGGL(k_hist,    dim3(2348), dim3(256), 0, stream, rel, blockhist, bucket,
                       big ? s2d : (int*)nullptr);
    hipLaunchKernelGGL(k_scan1,   dim3(NUM_RELS), dim3(64), 0, stream, blockhist, meta);
    hipLaunchKernelGGL(k_scan2,   dim3(1), dim3(64), 0, stream, meta);
    hipLaunchKernelGGL(k_scatter_det, dim3(NB), dim3(256), 0, stream, rel, meta, blockhist,
                       bucket, big ? inv : (int*)nullptr);
    hipLaunchKernelGGL(k_build_wt, dim3(576), dim3(256), 0, stream, wgt, wcmp, rw, Wt);
    hipLaunchKernelGGL(k_root_mfma, dim3((N_NODES + 127) / 128), dim3(256), 0, stream,
                       hb, Wt, bias, out);

    if (big) {
        hipLaunchKernelGGL(k_zero,        dim3(NB1),  dim3(256), 0, stream, cnt);
        hipLaunchKernelGGL(k_hist_dst,    dim3(2344), dim3(256), 0, stream, dst, cnt);
        hipLaunchKernelGGL(k_s1,          dim3(NB1),  dim3(256), 0, stream, cnt, bsum);
        hipLaunchKernelGGL(k_s2,          dim3(1),    dim3(64),  0, stream, bsum, bbase, offs);
        hipLaunchKernelGGL(k_s3,          dim3(NB1),  dim3(256), 0, stream, cnt, bbase, offs, cursor);
        hipLaunchKernelGGL(k_scatter_dst, dim3(2344), dim3(256), 0, stream, dst, inv, cursor, s2d);
        hipLaunchKernelGGL(k_edge_msg,    dim3(BUCKET_CAP / 128), dim3(256), 0, stream,
                           hb, Wt, src, meta, bucket, s2d, msgd);
        hipLaunchKernelGGL(k_gather_dst,  dim3((N_NODES + 3) / 4), dim3(256), 0, stream,
                           offs, msgd, out);
    } else {
        hipLaunchKernelGGL(k_edge_atomic, dim3(BUCKET_CAP / 128), dim3(256), 0, stream,
                           hb, Wt, src, dst, meta, bucket, out);
        hipLaunchKernelGGL(k_relu, dim3(N_NODES * FEAT / 4 / 256), dim3(256), 0, stream, out);
    }
}

// Round 5
// 335.404 us; speedup vs baseline: 4.7851x; 1.2539x over previous
//
#include <hip/hip_runtime.h>
#include <hip/hip_bf16.h>

#define N_NODES 100000
#define N_EDGES 600000
#define FEAT 128
#define NUM_RELS 8
#define NUM_BASES 4
#define NB 2344                          // ceil(N_EDGES/256)
#define PAD 128                          // relation region padding (block tile)
#define BUCKET_CAP (N_EDGES + NUM_RELS * PAD)   // 601024
#define NB1 391                          // ceil(N_NODES/256)

typedef short bf16x8 __attribute__((ext_vector_type(8)));
typedef float f32x4  __attribute__((ext_vector_type(4)));

__device__ inline short f2bf(float x) {
    __hip_bfloat16 b = __float2bfloat16(x);
    return *reinterpret_cast<short*>(&b);
}
__device__ inline float bfbits2f(unsigned int u16) {
    unsigned int u = u16 << 16;
    return __int_as_float(u);
}

// ws layout (bytes):
//   Wt   bf16[9*128*128]      @ 0           294,912
//   hb   bf16[N*128]          @ 294,912     25.6 MB
//   meta int[32]              @ 25,894,912
//   bucket int[BUCKET_CAP]    @ 25,895,040
//   blockhist int[NB*8]       @ 28,299,136
//   inv  int[N_EDGES]         @ 28,374,144
//   cnt  int[N_NODES]         @ 30,774,144
//   offs int[N_NODES+1+pad]   @ 31,174,144
//   cursor int[N_NODES]       @ 31,574,272
//   bsum int[NB1+pad]         @ 31,974,272
//   bbase int[NB1+pad]        @ 31,975,936
//   s2d  int[BUCKET_CAP]      @ 31,977,600
//   cb   int[32]              @ 34,381,696
//   msgd bf16[cap_slots*128]  @ 34,381,824  (chunked)
#define WS_BASE 34381824ull

// ============================ prep ============================

__global__ __launch_bounds__(256) void k_cast_h(const float* __restrict__ h,
                                                short* __restrict__ hb) {
    int i = blockIdx.x * 256 + threadIdx.x;
    if (i < N_NODES * FEAT / 8) {
        const float4* h4 = (const float4*)h;
        float4 v0 = h4[2 * i], v1 = h4[2 * i + 1];
        union { short s[8]; bf16x8 v; } u;
        u.s[0] = f2bf(v0.x); u.s[1] = f2bf(v0.y); u.s[2] = f2bf(v0.z); u.s[3] = f2bf(v0.w);
        u.s[4] = f2bf(v1.x); u.s[5] = f2bf(v1.y); u.s[6] = f2bf(v1.z); u.s[7] = f2bf(v1.w);
        ((bf16x8*)hb)[i] = u.v;
    }
}

__global__ __launch_bounds__(256) void k_hist(const int* __restrict__ rel,
                                              int* __restrict__ blockhist,
                                              int* __restrict__ bucket,
                                              int* __restrict__ s2d) {
    __shared__ int hist[NUM_RELS];
    if (threadIdx.x < NUM_RELS) hist[threadIdx.x] = 0;
    __syncthreads();
    int i = blockIdx.x * 256 + threadIdx.x;
    if (i < BUCKET_CAP) {
        bucket[i] = -1;
        if (s2d) s2d[i] = -1;
    }
    if (i < N_EDGES) atomicAdd(&hist[rel[i]], 1);      // LDS atomic
    __syncthreads();
    if (blockIdx.x < NB && threadIdx.x < NUM_RELS)
        blockhist[blockIdx.x * NUM_RELS + threadIdx.x] = hist[threadIdx.x];
}

__global__ __launch_bounds__(64) void k_scan1(int* __restrict__ blockhist,
                                              int* __restrict__ meta) {
    int r = blockIdx.x;
    int lane = threadIdx.x;
    int carry = 0;
    for (int c = 0; c < (NB + 63) / 64; ++c) {
        int idx = c * 64 + lane;
        int v = (idx < NB) ? blockhist[idx * NUM_RELS + r] : 0;
        int incl = v;
#pragma unroll
        for (int d = 1; d < 64; d <<= 1) {
            int t = __shfl_up(incl, d);
            if (lane >= d) incl += t;
        }
        int ex = incl - v + carry;
        if (idx < NB) blockhist[idx * NUM_RELS + r] = ex;
        carry += __shfl(incl, 63);
    }
    if (lane == 0) meta[r] = carry;
}

__global__ void k_scan2(int* __restrict__ meta) {
    if (blockIdx.x == 0 && threadIdx.x == 0) {
        int acc = 0;
        for (int r = 0; r < NUM_RELS; ++r) {
            meta[8 + r] = acc;
            acc += ((meta[r] + PAD - 1) / PAD) * PAD;
        }
        meta[16] = acc;
    }
}

__global__ __launch_bounds__(256) void k_scatter_det(const int* __restrict__ rel,
                                                     const int* __restrict__ meta,
                                                     const int* __restrict__ blockhist,
                                                     int* __restrict__ bucket,
                                                     int* __restrict__ inv) {
    __shared__ int cur[NUM_RELS];
    int b = blockIdx.x;
    if (threadIdx.x < NUM_RELS)
        cur[threadIdx.x] = meta[8 + threadIdx.x] + blockhist[b * NUM_RELS + threadIdx.x];
    __syncthreads();
    int i = b * 256 + threadIdx.x;
    if (i < N_EDGES) {
        int r = rel[i];
        int pos = atomicAdd(&cur[r], 1);               // LDS atomic
        bucket[pos] = i;
        if (inv) inv[i] = pos;
    }
}

__global__ __launch_bounds__(256) void k_build_wt(const float* __restrict__ weight,
                                                  const float* __restrict__ w_comp,
                                                  const float* __restrict__ rw,
                                                  short* __restrict__ Wt) {
    int idx = blockIdx.x * 256 + threadIdx.x;
    if (idx < 9 * FEAT * FEAT) {
        int r = idx >> 14;
        int e = idx & 16383;
        int i = e >> 7, o = e & 127;
        float acc;
        if (r < NUM_RELS) {
            acc = 0.f;
#pragma unroll
            for (int b = 0; b < NUM_BASES; ++b)
                acc += w_comp[r * NUM_BASES + b] * weight[b * FEAT * FEAT + e];
        } else {
            acc = rw[e];
        }
        Wt[(r << 14) + (o << 7) + i] = f2bf(acc);
    }
}

// ============================ dst counting-sort ============================

__global__ __launch_bounds__(256) void k_hist_dst(const int* __restrict__ dst,
                                                  int* __restrict__ cnt) {
    int i = blockIdx.x * 256 + threadIdx.x;
    if (i < N_EDGES) atomicAdd(&cnt[dst[i]], 1);       // 100K bins, ~6/bin
}

__global__ __launch_bounds__(256) void k_s1(const int* __restrict__ cnt,
                                            int* __restrict__ bsum) {
    int i = blockIdx.x * 256 + threadIdx.x;
    int v = (i < N_NODES) ? cnt[i] : 0;
#pragma unroll
    for (int d = 32; d; d >>= 1) v += __shfl_down(v, d);
    __shared__ int ws4[4];
    if ((threadIdx.x & 63) == 0) ws4[threadIdx.x >> 6] = v;
    __syncthreads();
    if (threadIdx.x == 0) bsum[blockIdx.x] = ws4[0] + ws4[1] + ws4[2] + ws4[3];
}

__global__ void k_s2(const int* __restrict__ bsum,
                     int* __restrict__ bbase,
                     int* __restrict__ offs) {
    if (blockIdx.x == 0 && threadIdx.x == 0) {
        int acc = 0;
        for (int b = 0; b < NB1; ++b) { bbase[b] = acc; acc += bsum[b]; }
        offs[N_NODES] = acc;                           // == N_EDGES
    }
}

__global__ __launch_bounds__(256) void k_s3(const int* __restrict__ cnt,
                                            const int* __restrict__ bbase,
                                            int* __restrict__ offs,
                                            int* __restrict__ cursor) {
    int i = blockIdx.x * 256 + threadIdx.x;
    int lane = threadIdx.x & 63, wid = threadIdx.x >> 6;
    int v = (i < N_NODES) ? cnt[i] : 0;
    int incl = v;
#pragma unroll
    for (int d = 1; d < 64; d <<= 1) {
        int t = __shfl_up(incl, d);
        if (lane >= d) incl += t;
    }
    __shared__ int wsum[4];
    if (lane == 63) wsum[wid] = incl;
    __syncthreads();
    if (threadIdx.x == 0) {
        int a = 0;
#pragma unroll
        for (int w = 0; w < 4; ++w) { int x = wsum[w]; wsum[w] = a; a += x; }
    }
    __syncthreads();
    int ex = incl - v + wsum[wid] + bbase[blockIdx.x];
    if (i < N_NODES) { offs[i] = ex; cursor[i] = ex; }
}

__global__ __launch_bounds__(256) void k_scatter_dst(const int* __restrict__ dst,
                                                     const int* __restrict__ inv,
                                                     int* __restrict__ cursor,
                                                     int* __restrict__ s2d) {
    int e = blockIdx.x * 256 + threadIdx.x;
    if (e < N_EDGES) {
        int p = atomicAdd(&cursor[dst[e]], 1);         // ~6-way contention
        s2d[inv[e]] = p;
    }
}

// chunk boundaries: cb[c] = first dst with offs[dst] >= c*stride (dst-aligned)
__global__ void k_chunkb(const int* __restrict__ offs, int* __restrict__ cb,
                         int chunks, int stride) {
    int c = threadIdx.x;
    if (c > chunks || blockIdx.x != 0) return;
    if (c == 0)       { cb[0] = 0; return; }
    if (c == chunks)  { cb[chunks] = N_NODES; return; }
    int target = c * stride;
    int lo = 0, hi = N_NODES;
    while (lo < hi) { int mid = (lo + hi) >> 1; if (offs[mid] < target) lo = mid + 1; else hi = mid; }
    cb[c] = lo;
}

// ============================ MFMA GEMMs ============================
// Column-ownership remap: B-fragment for n-tile nt, lane n16 reads weight row
// o = 8*n16 + nt  =>  lane n16 owns 8 CONSECUTIVE output cols [8*n16, 8*n16+8).
// LDS: row o holds 16 bf16x8 chunks; chunk c stored at (o<<4) + ((c + (o>>3)) & 15)
// (o>>3 == n16 at read time => conflict-free as before).

__global__ __launch_bounds__(256) void k_root_mfma(const short* __restrict__ hb,
                                                   const short* __restrict__ Wt,
                                                   const float* __restrict__ bias,
                                                   float* __restrict__ out) {
    __shared__ short lds[FEAT * FEAT];                  // 32 KB bf16
    const float4* s4 = (const float4*)(Wt + 8 * FEAT * FEAT);
    float4* l4 = (float4*)lds;
#pragma unroll
    for (int t = 0; t < 8; ++t) {
        int linear = threadIdx.x + t * 256;
        int o = linear >> 4, c = linear & 15;
        l4[(o << 4) + ((c + (o >> 3)) & 15)] = s4[linear];
    }
    __syncthreads();

    int wave = threadIdx.x >> 6, lane = threadIdx.x & 63;
    int quad = lane >> 4, n16 = lane & 15;
    int base = blockIdx.x * 128 + wave * 32;

    int rowA0 = base + n16;        if (rowA0 >= N_NODES) rowA0 = N_NODES - 1;
    int rowA1 = base + 16 + n16;   if (rowA1 >= N_NODES) rowA1 = N_NODES - 1;

    f32x4 acc[2][8];
#pragma unroll
    for (int mt = 0; mt < 2; ++mt)
#pragma unroll
        for (int nt = 0; nt < 8; ++nt) acc[mt][nt] = (f32x4)0.f;

    const bf16x8* a0p = (const bf16x8*)(hb + rowA0 * FEAT);
    const bf16x8* a1p = (const bf16x8*)(hb + rowA1 * FEAT);
    const bf16x8* bp  = (const bf16x8*)lds;
#pragma unroll
    for (int ks = 0; ks < 4; ++ks) {
        bf16x8 a0 = a0p[ks * 4 + quad];
        bf16x8 a1 = a1p[ks * 4 + quad];
        int sw = (ks * 4 + quad + n16) & 15;
#pragma unroll
        for (int nt = 0; nt < 8; ++nt) {
            int o = n16 * 8 + nt;
            bf16x8 b = bp[(o << 4) + sw];
            acc[0][nt] = __builtin_amdgcn_mfma_f32_16x16x32_bf16(a0, b, acc[0][nt], 0, 0, 0);
            acc[1][nt] = __builtin_amdgcn_mfma_f32_16x16x32_bf16(a1, b, acc[1][nt], 0, 0, 0);
        }
    }

    float bv[8];
#pragma unroll
    for (int nt = 0; nt < 8; ++nt) bv[nt] = bias[n16 * 8 + nt];

#pragma unroll
    for (int mt = 0; mt < 2; ++mt)
#pragma unroll
        for (int reg = 0; reg < 4; ++reg) {
            int node = base + mt * 16 + quad * 4 + reg;
            if (node < N_NODES) {
                float4 fa, fb;
                fa.x = acc[mt][0][reg] + bv[0]; fa.y = acc[mt][1][reg] + bv[1];
                fa.z = acc[mt][2][reg] + bv[2]; fa.w = acc[mt][3][reg] + bv[3];
                fb.x = acc[mt][4][reg] + bv[4]; fb.y = acc[mt][5][reg] + bv[5];
                fb.z = acc[mt][6][reg] + bv[6]; fb.w = acc[mt][7][reg] + bv[7];
                float* row = out + (size_t)node * FEAT + n16 * 8;
                *(float4*)row       = fa;
                *(float4*)(row + 4) = fb;
            }
        }
}

// phase A: edge GEMM -> coalesced bf16 stores into dst-sorted msg chunk
__global__ __launch_bounds__(256) void k_edge_msg(const short* __restrict__ hb,
                                                  const short* __restrict__ Wt,
                                                  const int* __restrict__ srcI,
                                                  const int* __restrict__ meta,
                                                  const int* __restrict__ bucket,
                                                  const int* __restrict__ s2d,
                                                  const int* __restrict__ offs,
                                                  const int* __restrict__ cb,
                                                  int chunk,
                                                  short* __restrict__ msgd) {
    __shared__ short lds[FEAT * FEAT];
    const int* bases = meta + 8;
    int ntot = bases[8];
    int p0 = blockIdx.x * 128;
    if (p0 >= ntot) return;

    int Plo = offs[cb[chunk]];
    int Phi = offs[cb[chunk + 1]];

    int rel = 0;
#pragma unroll
    for (int r = 1; r < NUM_RELS; ++r) if (p0 >= bases[r]) rel = r;

    const float4* s4 = (const float4*)(Wt + rel * FEAT * FEAT);
    float4* l4 = (float4*)lds;
#pragma unroll
    for (int t = 0; t < 8; ++t) {
        int linear = threadIdx.x + t * 256;
        int o = linear >> 4, c = linear & 15;
        l4[(o << 4) + ((c + (o >> 3)) & 15)] = s4[linear];
    }
    __syncthreads();

    int wave = threadIdx.x >> 6, lane = threadIdx.x & 63;
    int quad = lane >> 4, n16 = lane & 15;
    int pb = p0 + wave * 32;

    // per-lane store positions (rows quad*4+reg of each m-tile)
    int p8[2][4];
    bool any = false;
#pragma unroll
    for (int mt = 0; mt < 2; ++mt)
#pragma unroll
        for (int reg = 0; reg < 4; ++reg) {
            int p = s2d[pb + mt * 16 + quad * 4 + reg];
            p8[mt][reg] = p;
            any = any || (p >= Plo && p < Phi);
        }
    if (!__builtin_amdgcn_ballot_w64(any)) return;     // wave-uniform skip

    int src0 = 0, src1 = 0;
    { int e0 = bucket[pb + n16];      if (e0 >= 0) src0 = srcI[e0];
      int e1 = bucket[pb + 16 + n16]; if (e1 >= 0) src1 = srcI[e1]; }

    f32x4 acc[2][8];
#pragma unroll
    for (int mt = 0; mt < 2; ++mt)
#pragma unroll
        for (int nt = 0; nt < 8; ++nt) acc[mt][nt] = (f32x4)0.f;

    const bf16x8* a0p = (const bf16x8*)(hb + src0 * FEAT);
    const bf16x8* a1p = (const bf16x8*)(hb + src1 * FEAT);
    const bf16x8* bp  = (const bf16x8*)lds;
#pragma unroll
    for (int ks = 0; ks < 4; ++ks) {
        bf16x8 a0 = a0p[ks * 4 + quad];
        bf16x8 a1 = a1p[ks * 4 + quad];
        int sw = (ks * 4 + quad + n16) & 15;
#pragma unroll
        for (int nt = 0; nt < 8; ++nt) {
            int o = n16 * 8 + nt;
            bf16x8 b = bp[(o << 4) + sw];
            acc[0][nt] = __builtin_amdgcn_mfma_f32_16x16x32_bf16(a0, b, acc[0][nt], 0, 0, 0);
            acc[1][nt] = __builtin_amdgcn_mfma_f32_16x16x32_bf16(a1, b, acc[1][nt], 0, 0, 0);
        }
    }

#pragma unroll
    for (int mt = 0; mt < 2; ++mt)
#pragma unroll
        for (int reg = 0; reg < 4; ++reg) {
            int p = p8[mt][reg];
            if (p >= Plo && p < Phi) {
                union { short s[8]; bf16x8 v; } u;
#pragma unroll
                for (int nt = 0; nt < 8; ++nt) u.s[nt] = f2bf(acc[mt][nt][reg]);
                short* row = msgd + (size_t)(p - Plo) * FEAT;
                ((bf16x8*)row)[n16] = u.v;             // 16 B store, cols 8*n16..+7
            }
        }
}

// phase B: one wave per dst — contiguous bf16 message run + root + relu
__global__ __launch_bounds__(256) void k_gather_dst(const int* __restrict__ offs,
                                                    const short* __restrict__ msgd,
                                                    const int* __restrict__ cb,
                                                    int chunk,
                                                    float* __restrict__ out) {
    int wid = threadIdx.x >> 6, lane = threadIdx.x & 63;
    int d = blockIdx.x * 4 + wid;
    int dlo = cb[chunk], dhi = cb[chunk + 1];
    if (d < dlo || d >= dhi) return;
    int Plo = offs[dlo];
    int s = offs[d], e = offs[d + 1];
    float2 a = *(const float2*)(out + (size_t)d * FEAT + 2 * lane);
    for (int i = s; i < e; ++i) {
        unsigned int v = ((const unsigned int*)(msgd + (size_t)(i - Plo) * FEAT))[lane];
        a.x += bfbits2f(v & 0xffffu);
        a.y += bfbits2f(v >> 16);
    }
    a.x = fmaxf(a.x, 0.f);
    a.y = fmaxf(a.y, 0.f);
    *(float2*)(out + (size_t)d * FEAT + 2 * lane) = a;
}

// ============================ fallback (small ws): atomic scatter ============================

__global__ __launch_bounds__(256) void k_edge_atomic(const short* __restrict__ hb,
                                                     const short* __restrict__ Wt,
                                                     const int* __restrict__ srcI,
                                                     const int* __restrict__ dstI,
                                                     const int* __restrict__ meta,
                                                     const int* __restrict__ bucket,
                                                     float* __restrict__ out) {
    __shared__ short lds[FEAT * FEAT];
    const int* bases = meta + 8;
    int ntot = bases[8];
    int p0 = blockIdx.x * 128;
    if (p0 >= ntot) return;

    int rel = 0;
#pragma unroll
    for (int r = 1; r < NUM_RELS; ++r) if (p0 >= bases[r]) rel = r;

    const float4* s4 = (const float4*)(Wt + rel * FEAT * FEAT);
    float4* l4 = (float4*)lds;
#pragma unroll
    for (int t = 0; t < 8; ++t) {
        int linear = threadIdx.x + t * 256;
        int o = linear >> 4, c = linear & 15;
        l4[(o << 4) + ((c + (o >> 3)) & 15)] = s4[linear];
    }
    __syncthreads();

    int wave = threadIdx.x >> 6, lane = threadIdx.x & 63;
    int quad = lane >> 4, n16 = lane & 15;
    int pb = p0 + wave * 32;

    int src0 = 0, src1 = 0;
    { int e0 = bucket[pb + n16];      if (e0 >= 0) src0 = srcI[e0];
      int e1 = bucket[pb + 16 + n16]; if (e1 >= 0) src1 = srcI[e1]; }

    int dstv[2][4];
#pragma unroll
    for (int mt = 0; mt < 2; ++mt)
#pragma unroll
        for (int reg = 0; reg < 4; ++reg) {
            int e = bucket[pb + mt * 16 + quad * 4 + reg];
            dstv[mt][reg] = (e >= 0) ? dstI[e] : -1;
        }

    f32x4 acc[2][8];
#pragma unroll
    for (int mt = 0; mt < 2; ++mt)
#pragma unroll
        for (int nt = 0; nt < 8; ++nt) acc[mt][nt] = (f32x4)0.f;

    const bf16x8* a0p = (const bf16x8*)(hb + src0 * FEAT);
    const bf16x8* a1p = (const bf16x8*)(hb + src1 * FEAT);
    const bf16x8* bp  = (const bf16x8*)lds;
#pragma unroll
    for (int ks = 0; ks < 4; ++ks) {
        bf16x8 a0 = a0p[ks * 4 + quad];
        bf16x8 a1 = a1p[ks * 4 + quad];
        int sw = (ks * 4 + quad + n16) & 15;
#pragma unroll
        for (int nt = 0; nt < 8; ++nt) {
            int o = n16 * 8 + nt;
            bf16x8 b = bp[(o << 4) + sw];
            acc[0][nt] = __builtin_amdgcn_mfma_f32_16x16x32_bf16(a0, b, acc[0][nt], 0, 0, 0);
            acc[1][nt] = __builtin_amdgcn_mfma_f32_16x16x32_bf16(a1, b, acc[1][nt], 0, 0, 0);
        }
    }

#pragma unroll
    for (int mt = 0; mt < 2; ++mt)
#pragma unroll
        for (int reg = 0; reg < 4; ++reg) {
            int d = dstv[mt][reg];
            if (d >= 0) {
                float* row = out + (size_t)d * FEAT + n16 * 8;
#pragma unroll
                for (int nt = 0; nt < 8; ++nt)
                    atomicAdd(row + nt, acc[mt][nt][reg]);
            }
        }
}

__global__ __launch_bounds__(256) void k_relu(float* __restrict__ out) {
    int i = blockIdx.x * 256 + threadIdx.x;
    if (i < N_NODES * FEAT / 4) {
        float4* o4 = (float4*)out;
        float4 v = o4[i];
        v.x = fmaxf(v.x, 0.f);
        v.y = fmaxf(v.y, 0.f);
        v.z = fmaxf(v.z, 0.f);
        v.w = fmaxf(v.w, 0.f);
        o4[i] = v;
    }
}

// ============================ launch ============================

extern "C" void kernel_launch(void* const* d_in, const int* in_sizes, int n_in,
                              void* d_out, int out_size, void* d_ws, size_t ws_size,
                              hipStream_t stream) {
    const float* h    = (const float*)d_in[0];
    const float* wgt  = (const float*)d_in[1];
    const float* wcmp = (const float*)d_in[2];
    const float* rw   = (const float*)d_in[3];
    const float* bias = (const float*)d_in[4];
    const int*   src  = (const int*)d_in[5];
    const int*   dst  = (const int*)d_in[6];
    const int*   rel  = (const int*)d_in[7];
    float* out = (float*)d_out;

    char* ws = (char*)d_ws;
    short* Wt        = (short*)(ws + 0);
    short* hb        = (short*)(ws + 294912);
    int*   meta      = (int*)(ws + 25894912);
    int*   bucket    = (int*)(ws + 25895040);
    int*   blockhist = (int*)(ws + 28299136);
    int*   inv       = (int*)(ws + 28374144);
    int*   cnt       = (int*)(ws + 30774144);
    int*   offs      = (int*)(ws + 31174144);
    int*   cursor    = (int*)(ws + 31574272);
    int*   bsum      = (int*)(ws + 31974272);
    int*   bbase     = (int*)(ws + 31975936);
    int*   s2d       = (int*)(ws + 31977600);
    int*   cb        = (int*)(ws + 34381696);
    short* msgd      = (short*)(ws + WS_BASE);

    // chunking: each msg slot = 128 bf16 = 256 B
    long long cap_slots = (ws_size > WS_BASE) ? (long long)((ws_size - WS_BASE) / 256) : 0;
    long long stride_ll = cap_slots - 8192;            // slack >= max single-dst run
    int chunks = 0;
    if (stride_ll >= 60000) {                          // cap passes at 10
        chunks = (int)((N_EDGES + stride_ll - 1) / stride_ll);
        if (chunks < 1) chunks = 1;
    }
    const bool big = chunks >= 1;
    const int stride = big ? (int)stride_ll : 1;

    hipLaunchKernelGGL(k_cast_h,  dim3(6250), dim3(256), 0, stream, h, hb);
    hipLaunchKernelGGL(k_hist,    dim3(2348), dim3(256), 0, stream, rel, blockhist, bucket,
                       big ? s2d : (int*)nullptr);
    hipLaunchKernelGGL(k_scan1,   dim3(NUM_RELS), dim3(64), 0, stream, blockhist, meta);
    hipLaunchKernelGGL(k_scan2,   dim3(1), dim3(64), 0, stream, meta);
    hipLaunchKernelGGL(k_scatter_det, dim3(NB), dim3(256), 0, stream, rel, meta, blockhist,
                       bucket, big ? inv : (int*)nullptr);
    hipLaunchKernelGGL(k_build_wt, dim3(576), dim3(256), 0, stream, wgt, wcmp, rw, Wt);
    hipLaunchKernelGGL(k_root_mfma, dim3((N_NODES + 127) / 128), dim3(256), 0, stream,
                       hb, Wt, bias, out);

    if (big) {
        hipMemsetAsync(cnt, 0, N_NODES * sizeof(int), stream);
        hipLaunchKernelGGL(k_hist_dst,    dim3(2344), dim3(256), 0, stream, dst, cnt);
        hipLaunchKernelGGL(k_s1,          dim3(NB1),  dim3(256), 0, stream, cnt, bsum);
        hipLaunchKernelGGL(k_s2,          dim3(1),    dim3(64),  0, stream, bsum, bbase, offs);
        hipLaunchKernelGGL(k_s3,          dim3(NB1),  dim3(256), 0, stream, cnt, bbase, offs, cursor);
        hipLaunchKernelGGL(k_scatter_dst, dim3(2344), dim3(256), 0, stream, dst, inv, cursor, s2d);
        hipLaunchKernelGGL(k_chunkb,      dim3(1),    dim3(64),  0, stream, offs, cb, chunks, stride);
        for (int c = 0; c < chunks; ++c) {
            hipLaunchKernelGGL(k_edge_msg,   dim3(BUCKET_CAP / 128), dim3(256), 0, stream,
                               hb, Wt, src, meta, bucket, s2d, offs, cb, c, msgd);
            hipLaunchKernelGGL(k_gather_dst, dim3((N_NODES + 3) / 4), dim3(256), 0, stream,
                               offs, msgd, cb, c, out);
        }
    } else {
        hipLaunchKernelGGL(k_edge_atomic, dim3(BUCKET_CAP / 128), dim3(256), 0, stream,
                           hb, Wt, src, dst, meta, bucket, out);
        hipLaunchKernelGGL(k_relu, dim3(N_NODES * FEAT / 4 / 256), dim3(256), 0, stream, out);
    }
}

// Round 6
// 286.209 us; speedup vs baseline: 5.6076x; 1.1719x over previous
//
#include <hip/hip_runtime.h>
#include <hip/hip_bf16.h>

#define N_NODES 100000
#define N_EDGES 600000
#define FEAT 128
#define NUM_RELS 8
#define NUM_BASES 4
#define NB1 391     // ceil(N_NODES/256)
#define NBE 2344    // ceil(N_EDGES/256)

typedef short bf16x8 __attribute__((ext_vector_type(8)));
typedef float f32x4  __attribute__((ext_vector_type(4)));

__device__ inline short f2bf(float x) {
    __hip_bfloat16 b = __float2bfloat16(x);
    return *reinterpret_cast<short*>(&b);
}
__device__ inline float bfbits2f(unsigned int u16) {
    return __int_as_float(u16 << 16);
}
__device__ inline unsigned int fbits(float x) { return __float_as_uint(x); }

// ws layout (bytes):
//   hb    bf16[N*128]        @ 0            25,600,000
//   Bt    bf16[5*128*128]    @ 25,600,000   163,840   ([kc][o][i'] transposed)
//   z     bf16[N*512]        @ 25,763,840   102,400,000  ([d][b*128+i])
//   srcs  int[E]             @ 128,163,840  2,400,000 (dst-sorted src)
//   coef  float4[E]          @ 130,563,840  9,600,000 (dst-sorted w_comp[rel])
//   cnt   int[N]             @ 140,163,840  400,000
//   offs  int[N+1 pad]       @ 140,563,840  400,128
//   cursor int[N]            @ 140,963,968  400,000
//   bsum  int[512]           @ 141,363,968  2,048
//   bbase int[512]           @ 141,366,016  2,048
// total ~141.4 MB (< observed ws >= ~190 MB from Round 5's single-chunk run)

// ---------- cast h -> bf16 ----------
__global__ __launch_bounds__(256) void k_cast_h(const float* __restrict__ h,
                                                short* __restrict__ hb) {
    int i = blockIdx.x * 256 + threadIdx.x;
    if (i < N_NODES * FEAT / 8) {
        const float4* h4 = (const float4*)h;
        float4 v0 = h4[2 * i], v1 = h4[2 * i + 1];
        union { short s[8]; bf16x8 v; } u;
        u.s[0] = f2bf(v0.x); u.s[1] = f2bf(v0.y); u.s[2] = f2bf(v0.z); u.s[3] = f2bf(v0.w);
        u.s[4] = f2bf(v1.x); u.s[5] = f2bf(v1.y); u.s[6] = f2bf(v1.z); u.s[7] = f2bf(v1.w);
        ((bf16x8*)hb)[i] = u.v;
    }
}

// ---------- build B^T: Bt[kc][o][i'] ; kc=0 root_weight, kc=1..4 weight[b] ----------
__global__ __launch_bounds__(256) void k_build_b(const float* __restrict__ weight,
                                                 const float* __restrict__ rw,
                                                 short* __restrict__ Bt) {
    int idx = blockIdx.x * 256 + threadIdx.x;
    if (idx < 5 * FEAT * FEAT) {
        int kc = idx >> 14;
        int e  = idx & 16383;
        int o  = e >> 7, ip = e & 127;
        float v = (kc == 0) ? rw[ip * FEAT + o]
                            : weight[(kc - 1) * FEAT * FEAT + ip * FEAT + o];
        Bt[idx] = f2bf(v);      // idx == kc*16384 + o*128 + ip
    }
}

// ---------- dst histogram ----------
__global__ __launch_bounds__(256) void k_hist_dst(const int* __restrict__ dst,
                                                  int* __restrict__ cnt) {
    int i = blockIdx.x * 256 + threadIdx.x;
    if (i < N_EDGES) atomicAdd(&cnt[dst[i]], 1);       // 100K bins, ~6/bin
}

__global__ __launch_bounds__(256) void k_s1(const int* __restrict__ cnt,
                                            int* __restrict__ bsum) {
    int i = blockIdx.x * 256 + threadIdx.x;
    int v = (i < N_NODES) ? cnt[i] : 0;
#pragma unroll
    for (int d = 32; d; d >>= 1) v += __shfl_down(v, d);
    __shared__ int w4[4];
    if ((threadIdx.x & 63) == 0) w4[threadIdx.x >> 6] = v;
    __syncthreads();
    if (threadIdx.x == 0) bsum[blockIdx.x] = w4[0] + w4[1] + w4[2] + w4[3];
}

__global__ void k_s2(const int* __restrict__ bsum,
                     int* __restrict__ bbase,
                     int* __restrict__ offs) {
    if (blockIdx.x == 0 && threadIdx.x == 0) {
        int acc = 0;
        for (int b = 0; b < NB1; ++b) { bbase[b] = acc; acc += bsum[b]; }
        offs[N_NODES] = acc;                           // == N_EDGES
    }
}

__global__ __launch_bounds__(256) void k_s3(const int* __restrict__ cnt,
                                            const int* __restrict__ bbase,
                                            int* __restrict__ offs,
                                            int* __restrict__ cursor) {
    int i = blockIdx.x * 256 + threadIdx.x;
    int lane = threadIdx.x & 63, wid = threadIdx.x >> 6;
    int v = (i < N_NODES) ? cnt[i] : 0;
    int incl = v;
#pragma unroll
    for (int d = 1; d < 64; d <<= 1) {
        int t = __shfl_up(incl, d);
        if (lane >= d) incl += t;
    }
    __shared__ int wsum[4];
    if (lane == 63) wsum[wid] = incl;
    __syncthreads();
    if (threadIdx.x == 0) {
        int a = 0;
#pragma unroll
        for (int w = 0; w < 4; ++w) { int x = wsum[w]; wsum[w] = a; a += x; }
    }
    __syncthreads();
    int ex = incl - v + wsum[wid] + bbase[blockIdx.x];
    if (i < N_NODES) { offs[i] = ex; cursor[i] = ex; }
}

// ---------- scatter: dst-sorted (src, w_comp[rel]) ----------
__global__ __launch_bounds__(256) void k_scatter_sorted(const int* __restrict__ src,
                                                        const int* __restrict__ dst,
                                                        const int* __restrict__ rel,
                                                        const float* __restrict__ wc,
                                                        int* __restrict__ cursor,
                                                        int* __restrict__ srcs,
                                                        float4* __restrict__ coef) {
    int e = blockIdx.x * 256 + threadIdx.x;
    if (e < N_EDGES) {
        int p = atomicAdd(&cursor[dst[e]], 1);         // ~6-way contention
        srcs[p] = src[e];
        int r = rel[e] * NUM_BASES;
        coef[p] = make_float4(wc[r], wc[r + 1], wc[r + 2], wc[r + 3]);
    }
}

// ---------- edge phase: z[d][b][:] = sum_{e->d} w_comp[rel,b] * h[src]  (1 wave/dst) ----------
__global__ __launch_bounds__(256) void k_edge_z(const int* __restrict__ offs,
                                                const int* __restrict__ srcs,
                                                const float4* __restrict__ coef,
                                                const short* __restrict__ hb,
                                                unsigned int* __restrict__ z_u32) {
    int wid = threadIdx.x >> 6, lane = threadIdx.x & 63;
    int d = blockIdx.x * 4 + wid;
    if (d >= N_NODES) return;
    int s = offs[d], e = offs[d + 1];

    float zx[4] = {0.f, 0.f, 0.f, 0.f};   // col 2*lane
    float zy[4] = {0.f, 0.f, 0.f, 0.f};   // col 2*lane+1

    int i = s;
    for (; i + 1 < e; i += 2) {            // 2-deep for load ILP
        int s0 = srcs[i], s1 = srcs[i + 1];
        float4 c0 = coef[i], c1 = coef[i + 1];
        unsigned int v0 = ((const unsigned int*)(hb + (size_t)s0 * FEAT))[lane];
        unsigned int v1 = ((const unsigned int*)(hb + (size_t)s1 * FEAT))[lane];
        float a0 = bfbits2f(v0 & 0xffffu), b0 = bfbits2f(v0 >> 16);
        float a1 = bfbits2f(v1 & 0xffffu), b1 = bfbits2f(v1 >> 16);
        zx[0] += c0.x * a0; zy[0] += c0.x * b0;
        zx[1] += c0.y * a0; zy[1] += c0.y * b0;
        zx[2] += c0.z * a0; zy[2] += c0.z * b0;
        zx[3] += c0.w * a0; zy[3] += c0.w * b0;
        zx[0] += c1.x * a1; zy[0] += c1.x * b1;
        zx[1] += c1.y * a1; zy[1] += c1.y * b1;
        zx[2] += c1.z * a1; zy[2] += c1.z * b1;
        zx[3] += c1.w * a1; zy[3] += c1.w * b1;
    }
    if (i < e) {
        int s0 = srcs[i];
        float4 c0 = coef[i];
        unsigned int v0 = ((const unsigned int*)(hb + (size_t)s0 * FEAT))[lane];
        float a0 = bfbits2f(v0 & 0xffffu), b0 = bfbits2f(v0 >> 16);
        zx[0] += c0.x * a0; zy[0] += c0.x * b0;
        zx[1] += c0.y * a0; zy[1] += c0.y * b0;
        zx[2] += c0.z * a0; zy[2] += c0.z * b0;
        zx[3] += c0.w * a0; zy[3] += c0.w * b0;
    }

    unsigned int* row = z_u32 + (size_t)d * 256;       // 512 bf16 = 256 u32
#pragma unroll
    for (int b = 0; b < 4; ++b) {
        unsigned int lo = ((unsigned int)(unsigned short)f2bf(zx[b]));
        unsigned int hi = ((unsigned int)(unsigned short)f2bf(zy[b])) << 16;
        row[b * 64 + lane] = lo | hi;                  // coalesced 256B per b
    }
}

// ---------- fused GEMM: out = relu([hb | z] @ Bt + bias), K=640 ----------
// B-fragment: lane n16 owns 8 consecutive out cols o=8*n16+nt.
// LDS swizzle: chunk c of row o stored at (o<<4) + ((c + (o>>3)) & 15).
__global__ __launch_bounds__(256) void k_gemm_fused(const short* __restrict__ hb,
                                                    const short* __restrict__ z,
                                                    const short* __restrict__ Bt,
                                                    const float* __restrict__ bias,
                                                    float* __restrict__ out) {
    __shared__ short lds[FEAT * FEAT];                  // 32 KB (one K-chunk of B^T)
    int wave = threadIdx.x >> 6, lane = threadIdx.x & 63;
    int quad = lane >> 4, n16 = lane & 15;
    int base = blockIdx.x * 128 + wave * 32;

    int rowA0 = base + n16;        if (rowA0 >= N_NODES) rowA0 = N_NODES - 1;
    int rowA1 = base + 16 + n16;   if (rowA1 >= N_NODES) rowA1 = N_NODES - 1;

    f32x4 acc[2][8];
#pragma unroll
    for (int mt = 0; mt < 2; ++mt)
#pragma unroll
        for (int nt = 0; nt < 8; ++nt) acc[mt][nt] = (f32x4)0.f;

    float4* l4 = (float4*)lds;
    const bf16x8* bp = (const bf16x8*)lds;

    for (int kc = 0; kc < 5; ++kc) {
        if (kc) __syncthreads();                        // drain reads before restage
        const float4* s4 = (const float4*)(Bt + kc * FEAT * FEAT);
#pragma unroll
        for (int t = 0; t < 8; ++t) {
            int linear = threadIdx.x + t * 256;
            int o = linear >> 4, c = linear & 15;
            l4[(o << 4) + ((c + (o >> 3)) & 15)] = s4[linear];
        }
        __syncthreads();

        const bf16x8* a0p = (kc == 0)
            ? (const bf16x8*)(hb + (size_t)rowA0 * FEAT)
            : (const bf16x8*)(z + (size_t)rowA0 * 512 + (kc - 1) * FEAT);
        const bf16x8* a1p = (kc == 0)
            ? (const bf16x8*)(hb + (size_t)rowA1 * FEAT)
            : (const bf16x8*)(z + (size_t)rowA1 * 512 + (kc - 1) * FEAT);

#pragma unroll
        for (int ks = 0; ks < 4; ++ks) {
            bf16x8 a0 = a0p[ks * 4 + quad];
            bf16x8 a1 = a1p[ks * 4 + quad];
            int sw = (ks * 4 + quad + n16) & 15;
#pragma unroll
            for (int nt = 0; nt < 8; ++nt) {
                int o = n16 * 8 + nt;
                bf16x8 b = bp[(o << 4) + sw];
                acc[0][nt] = __builtin_amdgcn_mfma_f32_16x16x32_bf16(a0, b, acc[0][nt], 0, 0, 0);
                acc[1][nt] = __builtin_amdgcn_mfma_f32_16x16x32_bf16(a1, b, acc[1][nt], 0, 0, 0);
            }
        }
    }

    float bv[8];
#pragma unroll
    for (int nt = 0; nt < 8; ++nt) bv[nt] = bias[n16 * 8 + nt];

#pragma unroll
    for (int mt = 0; mt < 2; ++mt)
#pragma unroll
        for (int reg = 0; reg < 4; ++reg) {
            int node = base + mt * 16 + quad * 4 + reg;
            if (node < N_NODES) {
                float4 fa, fb;
                fa.x = fmaxf(acc[mt][0][reg] + bv[0], 0.f);
                fa.y = fmaxf(acc[mt][1][reg] + bv[1], 0.f);
                fa.z = fmaxf(acc[mt][2][reg] + bv[2], 0.f);
                fa.w = fmaxf(acc[mt][3][reg] + bv[3], 0.f);
                fb.x = fmaxf(acc[mt][4][reg] + bv[4], 0.f);
                fb.y = fmaxf(acc[mt][5][reg] + bv[5], 0.f);
                fb.z = fmaxf(acc[mt][6][reg] + bv[6], 0.f);
                fb.w = fmaxf(acc[mt][7][reg] + bv[7], 0.f);
                float* row = out + (size_t)node * FEAT + n16 * 8;
                *(float4*)row       = fa;
                *(float4*)(row + 4) = fb;
            }
        }
}

// ============================ launch ============================

extern "C" void kernel_launch(void* const* d_in, const int* in_sizes, int n_in,
                              void* d_out, int out_size, void* d_ws, size_t ws_size,
                              hipStream_t stream) {
    const float* h    = (const float*)d_in[0];
    const float* wgt  = (const float*)d_in[1];
    const float* wcmp = (const float*)d_in[2];
    const float* rw   = (const float*)d_in[3];
    const float* bias = (const float*)d_in[4];
    const int*   src  = (const int*)d_in[5];
    const int*   dst  = (const int*)d_in[6];
    const int*   rel  = (const int*)d_in[7];
    float* out = (float*)d_out;

    char* ws = (char*)d_ws;
    short*        hb     = (short*)(ws + 0);
    short*        Bt     = (short*)(ws + 25600000ull);
    short*        z      = (short*)(ws + 25763840ull);
    unsigned int* z_u32  = (unsigned int*)z;
    int*          srcs   = (int*)(ws + 128163840ull);
    float4*       coef   = (float4*)(ws + 130563840ull);
    int*          cnt    = (int*)(ws + 140163840ull);
    int*          offs   = (int*)(ws + 140563840ull);
    int*          cursor = (int*)(ws + 140963968ull);
    int*          bsum   = (int*)(ws + 141363968ull);
    int*          bbase  = (int*)(ws + 141366016ull);

    hipLaunchKernelGGL(k_cast_h,   dim3(6250), dim3(256), 0, stream, h, hb);
    hipLaunchKernelGGL(k_build_b,  dim3(320),  dim3(256), 0, stream, wgt, rw, Bt);
    hipMemsetAsync(cnt, 0, N_NODES * sizeof(int), stream);
    hipLaunchKernelGGL(k_hist_dst, dim3(NBE),  dim3(256), 0, stream, dst, cnt);
    hipLaunchKernelGGL(k_s1,       dim3(NB1),  dim3(256), 0, stream, cnt, bsum);
    hipLaunchKernelGGL(k_s2,       dim3(1),    dim3(64),  0, stream, bsum, bbase, offs);
    hipLaunchKernelGGL(k_s3,       dim3(NB1),  dim3(256), 0, stream, cnt, bbase, offs, cursor);
    hipLaunchKernelGGL(k_scatter_sorted, dim3(NBE), dim3(256), 0, stream,
                       src, dst, rel, wcmp, cursor, srcs, coef);
    hipLaunchKernelGGL(k_edge_z,   dim3((N_NODES + 3) / 4), dim3(256), 0, stream,
                       offs, srcs, coef, hb, z_u32);
    hipLaunchKernelGGL(k_gemm_fused, dim3((N_NODES + 127) / 128), dim3(256), 0, stream,
                       hb, z, Bt, bias, out);
}